// Round 1
// 3814.445 us; speedup vs baseline: 1.0352x; 1.0352x over previous
//
#include <hip/hip_runtime.h>
#include <math.h>

// ---- model constants (fixed problem size) ----
#define Bc   8
#define Sc   512
#define Dc   768
#define Hc   12
#define DHc  64
#define FFc  3072
#define Lc   12

typedef float  floatx4 __attribute__((ext_vector_type(4)));
typedef short  shortx8 __attribute__((ext_vector_type(8)));
typedef short  shortx4 __attribute__((ext_vector_type(4)));
typedef __bf16 bf16x8  __attribute__((ext_vector_type(8)));

__device__ __forceinline__ short f2bf(float f) {
  union { float f; unsigned u; } x; x.f = f;
  unsigned r = x.u + 0x7fffu + ((x.u >> 16) & 1u);   // RNE
  return (short)(r >> 16);
}

// ---------------- weight transpose+convert: W f32 [K,N] -> Wt bf16 [N,K] ----
__global__ __launch_bounds__(256)
void wtr_k(const float* __restrict__ W, short* __restrict__ Wt, int K, int N) {
  __shared__ short sT[64 * 72];
  const int k0 = blockIdx.x * 64, n0 = blockIdx.y * 64;
  const long base = (long)blockIdx.z * K * N;
  W  += base;
  Wt += base;
  const int t = threadIdx.x;
  {
    int kr = t >> 4, nc = (t & 15) * 4;
    #pragma unroll
    for (int i = 0; i < 4; ++i) {
      int k = kr + i * 16;
      float4 v = *(const float4*)(W + (long)(k0 + k) * N + n0 + nc);
      shortx4 p; p.x = f2bf(v.x); p.y = f2bf(v.y); p.z = f2bf(v.z); p.w = f2bf(v.w);
      *(shortx4*)(sT + k * 72 + nc) = p;
    }
  }
  __syncthreads();
  {
    int nr = t >> 3, kc = (t & 7) * 8;
    #pragma unroll
    for (int i = 0; i < 2; ++i) {
      int n = nr + i * 32;
      shortx8 p;
      #pragma unroll
      for (int j = 0; j < 8; ++j) p[j] = sT[(kc + j) * 72 + n];
      *(shortx8*)(Wt + (long)(n0 + n) * K + k0 + kc) = p;
    }
  }
}

// ---------------- dense GEMM ----------------
// C[M,N] = A[M,K] @ B^T  (A bf16 [M][lda], B bf16 pre-transposed [N][lda]),
// tile 128x128x64, 256 threads = 4 waves 2x2, wave 64x64 via 4x4 MFMA 16x16x32.
#define LR 72   // LDS row stride (64 + 8 pad)

enum { EP_QKV, EP_ATOM, EP_GELU };

template<int EP>
__global__ __launch_bounds__(256, 2)
void gemm_k(const short* __restrict__ A, int lda,
            const short* __restrict__ B0, const short* __restrict__ B1,
            const short* __restrict__ B2,
            void* __restrict__ Cp,
            const float* __restrict__ bias0, const float* __restrict__ bias1,
            const float* __restrict__ bias2,
            int Nn, int Ksplit)
{
  __shared__ short sA[128 * LR];
  __shared__ short sB[128 * LR];

  const int tid = threadIdx.x;
  const int z   = blockIdx.z;
  const int m0  = blockIdx.y * 128;
  const int n0  = blockIdx.x * 128;

  const short* Bw;
  const float* bias;
  int kbase;
  if (EP == EP_QKV) {
    Bw   = (z == 0) ? B0 : (z == 1 ? B1 : B2);
    bias = (z == 0) ? bias0 : (z == 1 ? bias1 : bias2);
    kbase = 0;
  } else {
    Bw = B0; bias = bias0; kbase = z * Ksplit;
  }

  const short* Ag = A  + (long)m0 * lda + kbase;
  const short* Bg = Bw + (long)n0 * lda + kbase;

  floatx4 acc[4][4];
  #pragma unroll
  for (int i = 0; i < 4; ++i)
    #pragma unroll
    for (int j = 0; j < 4; ++j) acc[i][j] = (floatx4)0.f;

  const int wave = tid >> 6, lane = tid & 63;
  const int wm = (wave >> 1) * 64, wn = (wave & 1) * 64;
  const int quad = lane >> 4, r16 = lane & 15;
  const int sr = tid >> 3, scc = (tid & 7) * 8;   // staging row/col

  const int nkt = Ksplit / 64;
  for (int kt = 0; kt < nkt; ++kt) {
    const long ko_g = (long)kt * 64;
    #pragma unroll
    for (int i = 0; i < 4; ++i) {
      int r = sr + i * 32;
      *(shortx8*)(sA + r * LR + scc) = *(const shortx8*)(Ag + (long)r * lda + ko_g + scc);
    }
    #pragma unroll
    for (int i = 0; i < 4; ++i) {
      int r = sr + i * 32;
      *(shortx8*)(sB + r * LR + scc) = *(const shortx8*)(Bg + (long)r * lda + ko_g + scc);
    }
    __syncthreads();

    #pragma unroll
    for (int kc = 0; kc < 2; ++kc) {
      const int ko = kc * 32 + quad * 8;
      bf16x8 af[4], bv[4];
      #pragma unroll
      for (int mi = 0; mi < 4; ++mi)
        af[mi] = __builtin_bit_cast(bf16x8, *(const shortx8*)(sA + (wm + mi * 16 + r16) * LR + ko));
      #pragma unroll
      for (int ni = 0; ni < 4; ++ni)
        bv[ni] = __builtin_bit_cast(bf16x8, *(const shortx8*)(sB + (wn + ni * 16 + r16) * LR + ko));
      #pragma unroll
      for (int mi = 0; mi < 4; ++mi)
        #pragma unroll
        for (int ni = 0; ni < 4; ++ni)
          acc[mi][ni] = __builtin_amdgcn_mfma_f32_16x16x32_bf16(af[mi], bv[ni], acc[mi][ni], 0, 0, 0);
    }
    __syncthreads();
  }

  // ---- epilogue: C/D layout col=lane&15, row=quad*4+reg ----
  #pragma unroll
  for (int mi = 0; mi < 4; ++mi) {
    #pragma unroll
    for (int ni = 0; ni < 4; ++ni) {
      #pragma unroll
      for (int r = 0; r < 4; ++r) {
        int mm = m0 + wm + mi * 16 + quad * 4 + r;
        int nn = n0 + wn + ni * 16 + r16;
        float v = acc[mi][ni][r];
        if (EP == EP_QKV) {
          v += bias[nn];
          int b = mm >> 9, s = mm & 511;
          int hh = nn >> 6, dd = nn & 63;
          ((short*)Cp)[((((long)z * Bc + b) * Hc + hh) * Sc + s) * DHc + dd] = f2bf(v);
        } else if (EP == EP_ATOM) {
          atomicAdd(&((float*)Cp)[(long)mm * Nn + nn], v);
        } else if (EP == EP_GELU) {
          v += bias[nn];
          float g = 0.5f * v * (1.f + erff(v * 0.70710678118654752f));
          ((short*)Cp)[(long)mm * Nn + nn] = f2bf(g);
        }
      }
    }
  }
}

// ---------------- fused flash attention (unchanged) ----------------
#define HDL ((long)Bc * Hc * Sc * DHc)

__global__ __launch_bounds__(256, 2)
void attn_k(const short* __restrict__ qkv, const int* __restrict__ msk,
            short* __restrict__ ctx)
{
  __shared__ short sQ[128 * 72];
  __shared__ short sK[64 * 72];
  __shared__ short sV[64 * 72];   // transposed [dh][kn], rotated
  __shared__ short sP[128 * 72];

  const int tid = threadIdx.x;
  const int qt = blockIdx.x, bh = blockIdx.y;
  const int b = bh / Hc, hh = bh % Hc;
  const int wave = tid >> 6, lane = tid & 63;
  const int quad = lane >> 4, r16 = lane & 15;

  const short* Qg = qkv + ((long)bh * Sc + qt * 128) * DHc;
  const short* Kg = qkv + HDL + (long)bh * Sc * DHc;
  const short* Vg = qkv + 2 * HDL + (long)bh * Sc * DHc;

  #pragma unroll
  for (int i = 0; i < 4; ++i) {
    int id = tid + i * 256;
    int r = id >> 3, c = (id & 7) * 8;
    *(shortx8*)(sQ + r * 72 + c) = *(const shortx8*)(Qg + r * 64 + c);
  }

  floatx4 o[2][4];
  float m_old[2][4], l[2][4];
  #pragma unroll
  for (int mi = 0; mi < 2; ++mi) {
    #pragma unroll
    for (int nj = 0; nj < 4; ++nj) o[mi][nj] = (floatx4)0.f;
    #pragma unroll
    for (int r = 0; r < 4; ++r) { m_old[mi][r] = -3.0e38f; l[mi][r] = 0.f; }
  }

  for (int kt = 0; kt < 8; ++kt) {
    __syncthreads();
    #pragma unroll
    for (int i = 0; i < 2; ++i) {
      int id = tid + i * 256;
      int r = id >> 3, c = (id & 7) * 8;
      *(shortx8*)(sK + r * 72 + c) = *(const shortx8*)(Kg + (kt * 64 + r) * 64 + c);
    }
    #pragma unroll
    for (int i = 0; i < 2; ++i) {
      int id = tid + i * 256;
      int r = id >> 3, c8 = id & 7;
      shortx8 v = *(const shortx8*)(Vg + (kt * 64 + r) * 64 + c8 * 8);
      #pragma unroll
      for (int j = 0; j < 8; ++j) {
        int kn2 = (r + 8 * ((j + c8) & 7)) & 63;
        sV[(c8 * 8 + j) * 72 + kn2] = v[j];
      }
    }
    __syncthreads();

    floatx4 s[2][4];
    #pragma unroll
    for (int mi = 0; mi < 2; ++mi)
      #pragma unroll
      for (int ni = 0; ni < 4; ++ni) s[mi][ni] = (floatx4)0.f;
    #pragma unroll
    for (int kc = 0; kc < 2; ++kc) {
      const int ko = kc * 32 + quad * 8;
      bf16x8 aq[2], bk[4];
      #pragma unroll
      for (int mi = 0; mi < 2; ++mi)
        aq[mi] = __builtin_bit_cast(bf16x8, *(const shortx8*)(sQ + (wave * 32 + mi * 16 + r16) * 72 + ko));
      #pragma unroll
      for (int ni = 0; ni < 4; ++ni)
        bk[ni] = __builtin_bit_cast(bf16x8, *(const shortx8*)(sK + (ni * 16 + r16) * 72 + ko));
      #pragma unroll
      for (int mi = 0; mi < 2; ++mi)
        #pragma unroll
        for (int ni = 0; ni < 4; ++ni)
          s[mi][ni] = __builtin_amdgcn_mfma_f32_16x16x32_bf16(aq[mi], bk[ni], s[mi][ni], 0, 0, 0);
    }

    float mv[4];
    #pragma unroll
    for (int ni = 0; ni < 4; ++ni)
      mv[ni] = (float)msk[b * Sc + kt * 64 + ni * 16 + r16];

    #pragma unroll
    for (int mi = 0; mi < 2; ++mi) {
      #pragma unroll
      for (int r = 0; r < 4; ++r) {
        float mx = fmaxf(fmaxf(s[mi][0][r], s[mi][1][r]), fmaxf(s[mi][2][r], s[mi][3][r]));
        mx *= 0.125f;
        #pragma unroll
        for (int off = 1; off <= 8; off <<= 1) mx = fmaxf(mx, __shfl_xor(mx, off));
        float mn = fmaxf(m_old[mi][r], mx);
        float al = __expf(m_old[mi][r] - mn);
        m_old[mi][r] = mn;
        float rs = 0.f;
        #pragma unroll
        for (int ni = 0; ni < 4; ++ni) {
          float p = __expf(fmaf(s[mi][ni][r], 0.125f, -mn)) * mv[ni];
          s[mi][ni][r] = p;
          rs += p;
        }
        #pragma unroll
        for (int off = 1; off <= 8; off <<= 1) rs += __shfl_xor(rs, off);
        l[mi][r] = l[mi][r] * al + rs;
        #pragma unroll
        for (int nj = 0; nj < 4; ++nj) o[mi][nj][r] *= al;
        int row = wave * 32 + mi * 16 + quad * 4 + r;
        #pragma unroll
        for (int ni = 0; ni < 4; ++ni)
          sP[row * 72 + ni * 16 + r16] = f2bf(s[mi][ni][r]);
      }
    }
    __syncthreads();

    #pragma unroll
    for (int kc = 0; kc < 2; ++kc) {
      const int ko = kc * 32 + quad * 8;
      bf16x8 ap[2], bv[4];
      #pragma unroll
      for (int mi = 0; mi < 2; ++mi)
        ap[mi] = __builtin_bit_cast(bf16x8, *(const shortx8*)(sP + (wave * 32 + mi * 16 + r16) * 72 + ko));
      #pragma unroll
      for (int nj = 0; nj < 4; ++nj) {
        int dh = nj * 16 + r16;
        int f = (dh + (dh >> 3)) & 7;
        int base = (ko + 8 * f) & 63;
        bv[nj] = __builtin_bit_cast(bf16x8, *(const shortx8*)(sV + dh * 72 + base));
      }
      #pragma unroll
      for (int mi = 0; mi < 2; ++mi)
        #pragma unroll
        for (int nj = 0; nj < 4; ++nj)
          o[mi][nj] = __builtin_amdgcn_mfma_f32_16x16x32_bf16(ap[mi], bv[nj], o[mi][nj], 0, 0, 0);
    }
  }

  #pragma unroll
  for (int mi = 0; mi < 2; ++mi) {
    #pragma unroll
    for (int r = 0; r < 4; ++r) {
      float inv = 1.f / fmaxf(l[mi][r], 1e-20f);
      int row = qt * 128 + wave * 32 + mi * 16 + quad * 4 + r;
      #pragma unroll
      for (int nj = 0; nj < 4; ++nj) {
        int col = hh * 64 + nj * 16 + r16;
        ctx[((long)b * Sc + row) * Dc + col] = f2bf(o[mi][nj][r] * inv);
      }
    }
  }
}

// ---------------- reductions / LN ----------------
__device__ __forceinline__ void block_red2(float& s, float& ss) {
  #pragma unroll
  for (int off = 32; off; off >>= 1) {
    s  += __shfl_xor(s, off);
    ss += __shfl_xor(ss, off);
  }
  __shared__ float rs[4], rss[4];
  int wave = threadIdx.x >> 6, lane = threadIdx.x & 63;
  __syncthreads();
  if (lane == 0) { rs[wave] = s; rss[wave] = ss; }
  __syncthreads();
  s  = rs[0] + rs[1] + rs[2] + rs[3];
  ss = rss[0] + rss[1] + rss[2] + rss[3];
}

__device__ __forceinline__ void ln3_dual(float a0, float a1, float a2,
                                         const float* __restrict__ g,
                                         const float* __restrict__ bb,
                                         float* __restrict__ outf,
                                         short* __restrict__ outb, int tid) {
  float s = a0 + a1 + a2;
  float ss = a0 * a0 + a1 * a1 + a2 * a2;
  block_red2(s, ss);
  float mu  = s * (1.f / 768.f);
  float var = ss * (1.f / 768.f) - mu * mu;
  float rstd = rsqrtf(var + 1e-12f);
  float y0 = (a0 - mu) * rstd * g[tid]       + bb[tid];
  float y1 = (a1 - mu) * rstd * g[tid + 256] + bb[tid + 256];
  float y2 = (a2 - mu) * rstd * g[tid + 512] + bb[tid + 512];
  outf[tid] = y0; outf[tid + 256] = y1; outf[tid + 512] = y2;
  outb[tid] = f2bf(y0); outb[tid + 256] = f2bf(y1); outb[tid + 512] = f2bf(y2);
}

// reduce (from atomically-accumulated t1) + bias + residual + LN; re-zeros t1
__global__ __launch_bounds__(256)
void red_ln_k(float* __restrict__ t1, const float* __restrict__ res,
              const float* __restrict__ bias,
              const float* __restrict__ g, const float* __restrict__ bb,
              float* __restrict__ outf, short* __restrict__ outb) {
  long base = (long)blockIdx.x * Dc;
  int tid = threadIdx.x;
  float a0 = t1[base + tid]       + bias[tid]       + res[base + tid];
  float a1 = t1[base + tid + 256] + bias[tid + 256] + res[base + tid + 256];
  float a2 = t1[base + tid + 512] + bias[tid + 512] + res[base + tid + 512];
  t1[base + tid] = 0.f; t1[base + tid + 256] = 0.f; t1[base + tid + 512] = 0.f;
  ln3_dual(a0, a1, a2, g, bb, outf + base, outb + base, tid);
}

__global__ __launch_bounds__(256)
void embed_k(const int* __restrict__ ids, const float* __restrict__ we,
             const float* __restrict__ pe, const float* __restrict__ te,
             const float* __restrict__ g, const float* __restrict__ bb,
             float* __restrict__ y, short* __restrict__ yb) {
  int row = blockIdx.x, tid = threadIdx.x;
  int s = row & 511;
  long wo = (long)ids[row] * Dc;
  long po = (long)s * Dc;
  float a0 = we[wo + tid]       + pe[po + tid]       + te[tid];
  float a1 = we[wo + tid + 256] + pe[po + tid + 256] + te[tid + 256];
  float a2 = we[wo + tid + 512] + pe[po + tid + 512] + te[tid + 512];
  ln3_dual(a0, a1, a2, g, bb, y + (long)row * Dc, yb + (long)row * Dc, tid);
}

// ---------------- mean pooling, two-phase (parallelized) ----------------
// phase 1: grid (16, B) — each block sums a 32-row S-chunk (masked) into
// partial[b][chunk][768]. 128 blocks instead of 8; coalesced f32 reads.
__global__ __launch_bounds__(256)
void pool1_k(const float* __restrict__ h, const int* __restrict__ msk,
             float* __restrict__ part) {
  const int chunk = blockIdx.x, b = blockIdx.y, tid = threadIdx.x;
  const float* hb = h + ((long)b * Sc + chunk * 32) * Dc;
  const int*   mb = msk + b * Sc + chunk * 32;
  float a0 = 0.f, a1 = 0.f, a2 = 0.f;
  for (int s = 0; s < 32; ++s) {
    float mk = (float)mb[s];
    if (mk != 0.f) {
      const float* hr = hb + (long)s * Dc;
      a0 += hr[tid] * mk; a1 += hr[tid + 256] * mk; a2 += hr[tid + 512] * mk;
    }
  }
  float* pr = part + (long)(b * 16 + chunk) * Dc;
  pr[tid] = a0; pr[tid + 256] = a1; pr[tid + 512] = a2;
}

// phase 2: grid B — sum 16 partials, divide by mask count, L2-normalize.
__global__ __launch_bounds__(256)
void pool2_k(const float* __restrict__ part, const int* __restrict__ msk,
             float* __restrict__ out) {
  const int b = blockIdx.x, tid = threadIdx.x;
  float cnt = 0.f, d0 = 0.f;
  for (int s = tid; s < Sc; s += 256) cnt += (float)msk[b * Sc + s];
  block_red2(cnt, d0);
  float a0 = 0.f, a1 = 0.f, a2 = 0.f;
  const float* pb = part + (long)b * 16 * Dc;
  #pragma unroll
  for (int c = 0; c < 16; ++c) {
    a0 += pb[c * Dc + tid];
    a1 += pb[c * Dc + tid + 256];
    a2 += pb[c * Dc + tid + 512];
  }
  float dn = 1.f / fmaxf(cnt, 1e-6f);
  a0 *= dn; a1 *= dn; a2 *= dn;
  float ssq = a0 * a0 + a1 * a1 + a2 * a2, d1 = 0.f;
  block_red2(ssq, d1);
  float rn = 1.f / fmaxf(sqrtf(ssq), 1e-12f);
  out[b * Dc + tid]       = a0 * rn;
  out[b * Dc + tid + 256] = a1 * rn;
  out[b * Dc + tid + 512] = a2 * rn;
}

// ---------------- launcher ----------------
extern "C" void kernel_launch(void* const* d_in, const int* in_sizes, int n_in,
                              void* d_out, int out_size, void* d_ws, size_t ws_size,
                              hipStream_t stream)
{
  const int*   ids   = (const int*)d_in[0];
  const int*   amask = (const int*)d_in[1];
  const float* we    = (const float*)d_in[2];
  const float* pe    = (const float*)d_in[3];
  const float* te    = (const float*)d_in[4];
  const float* elg   = (const float*)d_in[5];
  const float* elb   = (const float*)d_in[6];
  const float* Wq    = (const float*)d_in[7];
  const float* bq    = (const float*)d_in[8];
  const float* Wk    = (const float*)d_in[9];
  const float* bk    = (const float*)d_in[10];
  const float* Wv    = (const float*)d_in[11];
  const float* bv    = (const float*)d_in[12];
  const float* Wo    = (const float*)d_in[13];
  const float* bo    = (const float*)d_in[14];
  const float* l1g   = (const float*)d_in[15];
  const float* l1b   = (const float*)d_in[16];
  const float* Wi    = (const float*)d_in[17];
  const float* bi    = (const float*)d_in[18];
  const float* Wf    = (const float*)d_in[19];
  const float* bfp   = (const float*)d_in[20];
  const float* l2g   = (const float*)d_in[21];
  const float* l2b   = (const float*)d_in[22];
  float* out = (float*)d_out;

  const long HD = (long)Bc * Sc * Dc;        // 3,145,728
  const long DD = (long)Dc * Dc;             // 589,824
  const long DF = (long)Dc * FFc;            // 2,359,296

  // --- workspace layout ---
  short* wsS = (short*)d_ws;
  short* WqT = wsS;                 // [L][768][768]
  short* WkT = WqT + Lc * DD;
  short* WvT = WkT + Lc * DD;
  short* WoT = WvT + Lc * DD;
  short* WiT = WoT + Lc * DD;       // [L][3072][768]
  short* WfT = WiT + Lc * DF;       // [L][768][3072]
  long wEnd = 4 * Lc * DD + 2 * Lc * DF;       // shorts (= 84,934,656)

  float* wsF  = (float*)d_ws;
  long fBase  = wEnd / 2;                       // float index (wEnd even)
  float* h    = wsF + fBase;                    // HD f32 residual
  float* attn = h + HD;
  float* t1   = attn + HD;                      // split-K accumulator
  long sBase  = 2 * (fBase + 3 * HD);           // short index
  short* hb    = wsS + sBase;                   // HD bf16
  short* attnb = hb + HD;
  short* qkvb  = attnb + HD;                    // [3][B,H,S,DH]
  short* ctxb  = qkvb + 3 * HD;
  short* inter = ctxb + HD;                     // [B,S,FF]

  // --- once per call: zero the atomic accumulator, transpose weights ---
  hipMemsetAsync(t1, 0, HD * sizeof(float), stream);
  wtr_k<<<dim3(Dc / 64, Dc / 64, Lc), 256, 0, stream>>>(Wq, WqT, Dc, Dc);
  wtr_k<<<dim3(Dc / 64, Dc / 64, Lc), 256, 0, stream>>>(Wk, WkT, Dc, Dc);
  wtr_k<<<dim3(Dc / 64, Dc / 64, Lc), 256, 0, stream>>>(Wv, WvT, Dc, Dc);
  wtr_k<<<dim3(Dc / 64, Dc / 64, Lc), 256, 0, stream>>>(Wo, WoT, Dc, Dc);
  wtr_k<<<dim3(Dc / 64, FFc / 64, Lc), 256, 0, stream>>>(Wi, WiT, Dc, FFc);
  wtr_k<<<dim3(FFc / 64, Dc / 64, Lc), 256, 0, stream>>>(Wf, WfT, FFc, Dc);

  embed_k<<<Bc * Sc, 256, 0, stream>>>(ids, we, pe, te, elg, elb, h, hb);

  for (int l = 0; l < Lc; ++l) {
    // QKV: z selects W/bias; out bf16 [3][B,H,S,DH]
    gemm_k<EP_QKV><<<dim3(6, 32, 3), 256, 0, stream>>>(
        hb, Dc, WqT + l * DD, WkT + l * DD, WvT + l * DD, qkvb,
        bq + l * Dc, bk + l * Dc, bv + l * Dc, Dc, Dc);

    // fused flash attention -> ctx bf16 [B,S,D]
    attn_k<<<dim3(4, 96), 256, 0, stream>>>(qkvb, amask, ctxb);

    // ctx @ Wo, split-K=2, atomic accumulate into t1
    gemm_k<EP_ATOM><<<dim3(6, 32, 2), 256, 0, stream>>>(
        ctxb, Dc, WoT + l * DD, nullptr, nullptr, t1,
        nullptr, nullptr, nullptr, Dc, Dc / 2);

    // attn = LN(t1 + bo + h)  (re-zeros t1)
    red_ln_k<<<Bc * Sc, 256, 0, stream>>>(t1, h, bo + l * Dc,
                                          l1g + l * Dc, l1b + l * Dc, attn, attnb);

    // inter = gelu(attn @ Wi + bi) -> bf16
    gemm_k<EP_GELU><<<dim3(24, 32, 1), 256, 0, stream>>>(
        attnb, Dc, WiT + l * DF, nullptr, nullptr, inter,
        bi + l * FFc, nullptr, nullptr, FFc, Dc);

    // inter @ Wf, split-K=4, atomic accumulate into t1
    gemm_k<EP_ATOM><<<dim3(6, 32, 4), 256, 0, stream>>>(
        inter, FFc, WfT + l * DF, nullptr, nullptr, t1,
        nullptr, nullptr, nullptr, Dc, FFc / 4);

    // h = LN(t1 + bf + attn)  (re-zeros t1)
    red_ln_k<<<Bc * Sc, 256, 0, stream>>>(t1, attn, bfp + l * Dc,
                                          l2g + l * Dc, l2b + l * Dc, h, hb);
  }

  // mean-pool (two-phase, 128+8 blocks) + L2 normalize.
  // `attn` (f32, HD) is free after the last red_ln_k — reuse as partial buffer.
  pool1_k<<<dim3(16, Bc), 256, 0, stream>>>(h, amask, attn);
  pool2_k<<<Bc, 256, 0, stream>>>(attn, amask, out);
}

// Round 2
// 2763.645 us; speedup vs baseline: 1.4288x; 1.3802x over previous
//
#include <hip/hip_runtime.h>
#include <math.h>

// ---- model constants (fixed problem size) ----
#define Bc   8
#define Sc   512
#define Dc   768
#define Hc   12
#define DHc  64
#define FFc  3072
#define Lc   12

typedef float  floatx4 __attribute__((ext_vector_type(4)));
typedef short  shortx8 __attribute__((ext_vector_type(8)));
typedef short  shortx4 __attribute__((ext_vector_type(4)));
typedef __bf16 bf16x8  __attribute__((ext_vector_type(8)));

__device__ __forceinline__ short f2bf(float f) {
  union { float f; unsigned u; } x; x.f = f;
  unsigned r = x.u + 0x7fffu + ((x.u >> 16) & 1u);   // RNE
  return (short)(r >> 16);
}

// async global->LDS, 16B per lane. LDS dest must be wave-uniform base;
// HW writes base + lane*16. Global src is per-lane.
__device__ __forceinline__ void gl16(const void* g, void* l) {
  __builtin_amdgcn_global_load_lds(
      (const __attribute__((address_space(1))) void*)g,
      (__attribute__((address_space(3))) void*)l, 16, 0, 0);
}

// ---------------- weight transpose+convert: W f32 [K,N] -> Wt bf16 [N,K] ----
__global__ __launch_bounds__(256)
void wtr_k(const float* __restrict__ W, short* __restrict__ Wt, int K, int N) {
  __shared__ short sT[64 * 72];
  const int k0 = blockIdx.x * 64, n0 = blockIdx.y * 64;
  const long base = (long)blockIdx.z * K * N;
  W  += base;
  Wt += base;
  const int t = threadIdx.x;
  {
    int kr = t >> 4, nc = (t & 15) * 4;
    #pragma unroll
    for (int i = 0; i < 4; ++i) {
      int k = kr + i * 16;
      float4 v = *(const float4*)(W + (long)(k0 + k) * N + n0 + nc);
      shortx4 p; p.x = f2bf(v.x); p.y = f2bf(v.y); p.z = f2bf(v.z); p.w = f2bf(v.w);
      *(shortx4*)(sT + k * 72 + nc) = p;
    }
  }
  __syncthreads();
  {
    int nr = t >> 3, kc = (t & 7) * 8;
    #pragma unroll
    for (int i = 0; i < 2; ++i) {
      int n = nr + i * 32;
      shortx8 p;
      #pragma unroll
      for (int j = 0; j < 8; ++j) p[j] = sT[(kc + j) * 72 + n];
      *(shortx8*)(Wt + (long)(n0 + n) * K + k0 + kc) = p;
    }
  }
}

// ---------------- dense GEMM ----------------
// C[M,N] = A[M,K] @ B^T  (A bf16 [M][lda], B bf16 pre-transposed [N][lda]),
// tile 128x128x64, 256 threads = 4 waves 2x2, wave 64x64 via 4x4 MFMA 16x16x32.
// Staging via global_load_lds width=16 into LINEAR [128][64] LDS with an
// XOR-16B swizzle applied BOTH sides (rule #21): the per-lane global source
// column is pre-swizzled (col ^= 16B*(row&7)) and the ds_read address applies
// the same XOR. 16-way bank conflict -> 2-way (free).

enum { EP_QKV, EP_ATOM, EP_GELU };

template<int EP>
__global__ __launch_bounds__(256, 3)
void gemm_k(const short* __restrict__ A, int lda,
            const short* __restrict__ B0, const short* __restrict__ B1,
            const short* __restrict__ B2,
            void* __restrict__ Cp,
            const float* __restrict__ bias0, const float* __restrict__ bias1,
            const float* __restrict__ bias2,
            int Nn, int Ksplit)
{
  __shared__ short sA[128 * 64];
  __shared__ short sB[128 * 64];

  const int tid = threadIdx.x;
  const int z   = blockIdx.z;
  const int m0  = blockIdx.y * 128;
  const int n0  = blockIdx.x * 128;

  const short* Bw;
  const float* bias;
  int kbase;
  if (EP == EP_QKV) {
    Bw   = (z == 0) ? B0 : (z == 1 ? B1 : B2);
    bias = (z == 0) ? bias0 : (z == 1 ? bias1 : bias2);
    kbase = 0;
  } else {
    Bw = B0; bias = bias0; kbase = z * Ksplit;
  }

  const short* Ag = A  + (long)m0 * lda + kbase;
  const short* Bg = Bw + (long)n0 * lda + kbase;

  floatx4 acc[4][4];
  #pragma unroll
  for (int i = 0; i < 4; ++i)
    #pragma unroll
    for (int j = 0; j < 4; ++j) acc[i][j] = (floatx4)0.f;

  const int wave = tid >> 6, lane = tid & 63;
  const int wm = (wave >> 1) * 64, wn = (wave & 1) * 64;
  const int quad = lane >> 4, r16 = lane & 15;

  // staging geometry: wave w, iter i covers rows (w*4+i)*8 .. +8 of the tile.
  // lane l -> row offset l>>3, swizzled col (shorts) 8*((l&7)^(l>>3)).
  const int srow = lane >> 3;                    // 0..7
  const int scol = 8 * ((lane & 7) ^ srow);      // pre-swizzled source col

  const int nkt = Ksplit / 64;
  for (int kt = 0; kt < nkt; ++kt) {
    const long ko_g = (long)kt * 64;
    #pragma unroll
    for (int i = 0; i < 4; ++i) {
      int rb = (wave * 4 + i) * 8;               // tile row base of this 1KB chunk
      gl16(Ag + (long)(rb + srow) * lda + ko_g + scol, sA + (wave * 4 + i) * 512);
    }
    #pragma unroll
    for (int i = 0; i < 4; ++i) {
      int rb = (wave * 4 + i) * 8;
      gl16(Bg + (long)(rb + srow) * lda + ko_g + scol, sB + (wave * 4 + i) * 512);
    }
    __syncthreads();

    #pragma unroll
    for (int kc = 0; kc < 2; ++kc) {
      const int ko = kc * 32 + quad * 8;
      bf16x8 af[4], bv[4];
      #pragma unroll
      for (int mi = 0; mi < 4; ++mi) {
        int row = wm + mi * 16 + r16;
        af[mi] = __builtin_bit_cast(bf16x8,
            *(const shortx8*)(sA + row * 64 + (ko ^ (8 * (row & 7)))));
      }
      #pragma unroll
      for (int ni = 0; ni < 4; ++ni) {
        int row = wn + ni * 16 + r16;
        bv[ni] = __builtin_bit_cast(bf16x8,
            *(const shortx8*)(sB + row * 64 + (ko ^ (8 * (row & 7)))));
      }
      #pragma unroll
      for (int mi = 0; mi < 4; ++mi)
        #pragma unroll
        for (int ni = 0; ni < 4; ++ni)
          acc[mi][ni] = __builtin_amdgcn_mfma_f32_16x16x32_bf16(af[mi], bv[ni], acc[mi][ni], 0, 0, 0);
    }
    __syncthreads();
  }

  // ---- epilogue: C/D layout col=lane&15, row=quad*4+reg ----
  #pragma unroll
  for (int mi = 0; mi < 4; ++mi) {
    #pragma unroll
    for (int ni = 0; ni < 4; ++ni) {
      #pragma unroll
      for (int r = 0; r < 4; ++r) {
        int mm = m0 + wm + mi * 16 + quad * 4 + r;
        int nn = n0 + wn + ni * 16 + r16;
        float v = acc[mi][ni][r];
        if (EP == EP_QKV) {
          v += bias[nn];
          int b = mm >> 9, s = mm & 511;
          int hh = nn >> 6, dd = nn & 63;
          ((short*)Cp)[((((long)z * Bc + b) * Hc + hh) * Sc + s) * DHc + dd] = f2bf(v);
        } else if (EP == EP_ATOM) {
          atomicAdd(&((float*)Cp)[(long)mm * Nn + nn], v);
        } else if (EP == EP_GELU) {
          v += bias[nn];
          float g = 0.5f * v * (1.f + erff(v * 0.70710678118654752f));
          ((short*)Cp)[(long)mm * Nn + nn] = f2bf(g);
        }
      }
    }
  }
}

// ---------------- fused flash attention (unchanged) ----------------
#define HDL ((long)Bc * Hc * Sc * DHc)

__global__ __launch_bounds__(256, 2)
void attn_k(const short* __restrict__ qkv, const int* __restrict__ msk,
            short* __restrict__ ctx)
{
  __shared__ short sQ[128 * 72];
  __shared__ short sK[64 * 72];
  __shared__ short sV[64 * 72];   // transposed [dh][kn], rotated
  __shared__ short sP[128 * 72];

  const int tid = threadIdx.x;
  const int qt = blockIdx.x, bh = blockIdx.y;
  const int b = bh / Hc, hh = bh % Hc;
  const int wave = tid >> 6, lane = tid & 63;
  const int quad = lane >> 4, r16 = lane & 15;

  const short* Qg = qkv + ((long)bh * Sc + qt * 128) * DHc;
  const short* Kg = qkv + HDL + (long)bh * Sc * DHc;
  const short* Vg = qkv + 2 * HDL + (long)bh * Sc * DHc;

  #pragma unroll
  for (int i = 0; i < 4; ++i) {
    int id = tid + i * 256;
    int r = id >> 3, c = (id & 7) * 8;
    *(shortx8*)(sQ + r * 72 + c) = *(const shortx8*)(Qg + r * 64 + c);
  }

  floatx4 o[2][4];
  float m_old[2][4], l[2][4];
  #pragma unroll
  for (int mi = 0; mi < 2; ++mi) {
    #pragma unroll
    for (int nj = 0; nj < 4; ++nj) o[mi][nj] = (floatx4)0.f;
    #pragma unroll
    for (int r = 0; r < 4; ++r) { m_old[mi][r] = -3.0e38f; l[mi][r] = 0.f; }
  }

  for (int kt = 0; kt < 8; ++kt) {
    __syncthreads();
    #pragma unroll
    for (int i = 0; i < 2; ++i) {
      int id = tid + i * 256;
      int r = id >> 3, c = (id & 7) * 8;
      *(shortx8*)(sK + r * 72 + c) = *(const shortx8*)(Kg + (kt * 64 + r) * 64 + c);
    }
    #pragma unroll
    for (int i = 0; i < 2; ++i) {
      int id = tid + i * 256;
      int r = id >> 3, c8 = id & 7;
      shortx8 v = *(const shortx8*)(Vg + (kt * 64 + r) * 64 + c8 * 8);
      #pragma unroll
      for (int j = 0; j < 8; ++j) {
        int kn2 = (r + 8 * ((j + c8) & 7)) & 63;
        sV[(c8 * 8 + j) * 72 + kn2] = v[j];
      }
    }
    __syncthreads();

    floatx4 s[2][4];
    #pragma unroll
    for (int mi = 0; mi < 2; ++mi)
      #pragma unroll
      for (int ni = 0; ni < 4; ++ni) s[mi][ni] = (floatx4)0.f;
    #pragma unroll
    for (int kc = 0; kc < 2; ++kc) {
      const int ko = kc * 32 + quad * 8;
      bf16x8 aq[2], bk[4];
      #pragma unroll
      for (int mi = 0; mi < 2; ++mi)
        aq[mi] = __builtin_bit_cast(bf16x8, *(const shortx8*)(sQ + (wave * 32 + mi * 16 + r16) * 72 + ko));
      #pragma unroll
      for (int ni = 0; ni < 4; ++ni)
        bk[ni] = __builtin_bit_cast(bf16x8, *(const shortx8*)(sK + (ni * 16 + r16) * 72 + ko));
      #pragma unroll
      for (int mi = 0; mi < 2; ++mi)
        #pragma unroll
        for (int ni = 0; ni < 4; ++ni)
          s[mi][ni] = __builtin_amdgcn_mfma_f32_16x16x32_bf16(aq[mi], bk[ni], s[mi][ni], 0, 0, 0);
    }

    float mv[4];
    #pragma unroll
    for (int ni = 0; ni < 4; ++ni)
      mv[ni] = (float)msk[b * Sc + kt * 64 + ni * 16 + r16];

    #pragma unroll
    for (int mi = 0; mi < 2; ++mi) {
      #pragma unroll
      for (int r = 0; r < 4; ++r) {
        float mx = fmaxf(fmaxf(s[mi][0][r], s[mi][1][r]), fmaxf(s[mi][2][r], s[mi][3][r]));
        mx *= 0.125f;
        #pragma unroll
        for (int off = 1; off <= 8; off <<= 1) mx = fmaxf(mx, __shfl_xor(mx, off));
        float mn = fmaxf(m_old[mi][r], mx);
        float al = __expf(m_old[mi][r] - mn);
        m_old[mi][r] = mn;
        float rs = 0.f;
        #pragma unroll
        for (int ni = 0; ni < 4; ++ni) {
          float p = __expf(fmaf(s[mi][ni][r], 0.125f, -mn)) * mv[ni];
          s[mi][ni][r] = p;
          rs += p;
        }
        #pragma unroll
        for (int off = 1; off <= 8; off <<= 1) rs += __shfl_xor(rs, off);
        l[mi][r] = l[mi][r] * al + rs;
        #pragma unroll
        for (int nj = 0; nj < 4; ++nj) o[mi][nj][r] *= al;
        int row = wave * 32 + mi * 16 + quad * 4 + r;
        #pragma unroll
        for (int ni = 0; ni < 4; ++ni)
          sP[row * 72 + ni * 16 + r16] = f2bf(s[mi][ni][r]);
      }
    }
    __syncthreads();

    #pragma unroll
    for (int kc = 0; kc < 2; ++kc) {
      const int ko = kc * 32 + quad * 8;
      bf16x8 ap[2], bv[4];
      #pragma unroll
      for (int mi = 0; mi < 2; ++mi)
        ap[mi] = __builtin_bit_cast(bf16x8, *(const shortx8*)(sP + (wave * 32 + mi * 16 + r16) * 72 + ko));
      #pragma unroll
      for (int nj = 0; nj < 4; ++nj) {
        int dh = nj * 16 + r16;
        int f = (dh + (dh >> 3)) & 7;
        int base = (ko + 8 * f) & 63;
        bv[nj] = __builtin_bit_cast(bf16x8, *(const shortx8*)(sV + dh * 72 + base));
      }
      #pragma unroll
      for (int mi = 0; mi < 2; ++mi)
        #pragma unroll
        for (int nj = 0; nj < 4; ++nj)
          o[mi][nj] = __builtin_amdgcn_mfma_f32_16x16x32_bf16(ap[mi], bv[nj], o[mi][nj], 0, 0, 0);
    }
  }

  #pragma unroll
  for (int mi = 0; mi < 2; ++mi) {
    #pragma unroll
    for (int r = 0; r < 4; ++r) {
      float inv = 1.f / fmaxf(l[mi][r], 1e-20f);
      int row = qt * 128 + wave * 32 + mi * 16 + quad * 4 + r;
      #pragma unroll
      for (int nj = 0; nj < 4; ++nj) {
        int col = hh * 64 + nj * 16 + r16;
        ctx[((long)b * Sc + row) * Dc + col] = f2bf(o[mi][nj][r] * inv);
      }
    }
  }
}

// ---------------- reductions / LN ----------------
__device__ __forceinline__ void block_red2(float& s, float& ss) {
  #pragma unroll
  for (int off = 32; off; off >>= 1) {
    s  += __shfl_xor(s, off);
    ss += __shfl_xor(ss, off);
  }
  __shared__ float rs[4], rss[4];
  int wave = threadIdx.x >> 6, lane = threadIdx.x & 63;
  __syncthreads();
  if (lane == 0) { rs[wave] = s; rss[wave] = ss; }
  __syncthreads();
  s  = rs[0] + rs[1] + rs[2] + rs[3];
  ss = rss[0] + rss[1] + rss[2] + rss[3];
}

__device__ __forceinline__ void ln3_dual(float a0, float a1, float a2,
                                         const float* __restrict__ g,
                                         const float* __restrict__ bb,
                                         float* __restrict__ outf,
                                         short* __restrict__ outb, int tid) {
  float s = a0 + a1 + a2;
  float ss = a0 * a0 + a1 * a1 + a2 * a2;
  block_red2(s, ss);
  float mu  = s * (1.f / 768.f);
  float var = ss * (1.f / 768.f) - mu * mu;
  float rstd = rsqrtf(var + 1e-12f);
  float y0 = (a0 - mu) * rstd * g[tid]       + bb[tid];
  float y1 = (a1 - mu) * rstd * g[tid + 256] + bb[tid + 256];
  float y2 = (a2 - mu) * rstd * g[tid + 512] + bb[tid + 512];
  outf[tid] = y0; outf[tid + 256] = y1; outf[tid + 512] = y2;
  outb[tid] = f2bf(y0); outb[tid + 256] = f2bf(y1); outb[tid + 512] = f2bf(y2);
}

// reduce (from atomically-accumulated t1) + bias + residual + LN; re-zeros t1
__global__ __launch_bounds__(256)
void red_ln_k(float* __restrict__ t1, const float* __restrict__ res,
              const float* __restrict__ bias,
              const float* __restrict__ g, const float* __restrict__ bb,
              float* __restrict__ outf, short* __restrict__ outb) {
  long base = (long)blockIdx.x * Dc;
  int tid = threadIdx.x;
  float a0 = t1[base + tid]       + bias[tid]       + res[base + tid];
  float a1 = t1[base + tid + 256] + bias[tid + 256] + res[base + tid + 256];
  float a2 = t1[base + tid + 512] + bias[tid + 512] + res[base + tid + 512];
  t1[base + tid] = 0.f; t1[base + tid + 256] = 0.f; t1[base + tid + 512] = 0.f;
  ln3_dual(a0, a1, a2, g, bb, outf + base, outb + base, tid);
}

__global__ __launch_bounds__(256)
void embed_k(const int* __restrict__ ids, const float* __restrict__ we,
             const float* __restrict__ pe, const float* __restrict__ te,
             const float* __restrict__ g, const float* __restrict__ bb,
             float* __restrict__ y, short* __restrict__ yb) {
  int row = blockIdx.x, tid = threadIdx.x;
  int s = row & 511;
  long wo = (long)ids[row] * Dc;
  long po = (long)s * Dc;
  float a0 = we[wo + tid]       + pe[po + tid]       + te[tid];
  float a1 = we[wo + tid + 256] + pe[po + tid + 256] + te[tid + 256];
  float a2 = we[wo + tid + 512] + pe[po + tid + 512] + te[tid + 512];
  ln3_dual(a0, a1, a2, g, bb, y + (long)row * Dc, yb + (long)row * Dc, tid);
}

// ---------------- mean pooling, two-phase (parallelized) ----------------
__global__ __launch_bounds__(256)
void pool1_k(const float* __restrict__ h, const int* __restrict__ msk,
             float* __restrict__ part) {
  const int chunk = blockIdx.x, b = blockIdx.y, tid = threadIdx.x;
  const float* hb = h + ((long)b * Sc + chunk * 32) * Dc;
  const int*   mb = msk + b * Sc + chunk * 32;
  float a0 = 0.f, a1 = 0.f, a2 = 0.f;
  for (int s = 0; s < 32; ++s) {
    float mk = (float)mb[s];
    if (mk != 0.f) {
      const float* hr = hb + (long)s * Dc;
      a0 += hr[tid] * mk; a1 += hr[tid + 256] * mk; a2 += hr[tid + 512] * mk;
    }
  }
  float* pr = part + (long)(b * 16 + chunk) * Dc;
  pr[tid] = a0; pr[tid + 256] = a1; pr[tid + 512] = a2;
}

__global__ __launch_bounds__(256)
void pool2_k(const float* __restrict__ part, const int* __restrict__ msk,
             float* __restrict__ out) {
  const int b = blockIdx.x, tid = threadIdx.x;
  float cnt = 0.f, d0 = 0.f;
  for (int s = tid; s < Sc; s += 256) cnt += (float)msk[b * Sc + s];
  block_red2(cnt, d0);
  float a0 = 0.f, a1 = 0.f, a2 = 0.f;
  const float* pb = part + (long)b * 16 * Dc;
  #pragma unroll
  for (int c = 0; c < 16; ++c) {
    a0 += pb[c * Dc + tid];
    a1 += pb[c * Dc + tid + 256];
    a2 += pb[c * Dc + tid + 512];
  }
  float dn = 1.f / fmaxf(cnt, 1e-6f);
  a0 *= dn; a1 *= dn; a2 *= dn;
  float ssq = a0 * a0 + a1 * a1 + a2 * a2, d1 = 0.f;
  block_red2(ssq, d1);
  float rn = 1.f / fmaxf(sqrtf(ssq), 1e-12f);
  out[b * Dc + tid]       = a0 * rn;
  out[b * Dc + tid + 256] = a1 * rn;
  out[b * Dc + tid + 512] = a2 * rn;
}

// ---------------- launcher ----------------
extern "C" void kernel_launch(void* const* d_in, const int* in_sizes, int n_in,
                              void* d_out, int out_size, void* d_ws, size_t ws_size,
                              hipStream_t stream)
{
  const int*   ids   = (const int*)d_in[0];
  const int*   amask = (const int*)d_in[1];
  const float* we    = (const float*)d_in[2];
  const float* pe    = (const float*)d_in[3];
  const float* te    = (const float*)d_in[4];
  const float* elg   = (const float*)d_in[5];
  const float* elb   = (const float*)d_in[6];
  const float* Wq    = (const float*)d_in[7];
  const float* bq    = (const float*)d_in[8];
  const float* Wk    = (const float*)d_in[9];
  const float* bk    = (const float*)d_in[10];
  const float* Wv    = (const float*)d_in[11];
  const float* bv    = (const float*)d_in[12];
  const float* Wo    = (const float*)d_in[13];
  const float* bo    = (const float*)d_in[14];
  const float* l1g   = (const float*)d_in[15];
  const float* l1b   = (const float*)d_in[16];
  const float* Wi    = (const float*)d_in[17];
  const float* bi    = (const float*)d_in[18];
  const float* Wf    = (const float*)d_in[19];
  const float* bfp   = (const float*)d_in[20];
  const float* l2g   = (const float*)d_in[21];
  const float* l2b   = (const float*)d_in[22];
  float* out = (float*)d_out;

  const long HD = (long)Bc * Sc * Dc;        // 3,145,728
  const long DD = (long)Dc * Dc;             // 589,824
  const long DF = (long)Dc * FFc;            // 2,359,296

  // --- workspace layout ---
  short* wsS = (short*)d_ws;
  short* WqT = wsS;                 // [L][768][768]
  short* WkT = WqT + Lc * DD;
  short* WvT = WkT + Lc * DD;
  short* WoT = WvT + Lc * DD;
  short* WiT = WoT + Lc * DD;       // [L][3072][768]
  short* WfT = WiT + Lc * DF;       // [L][768][3072]
  long wEnd = 4 * Lc * DD + 2 * Lc * DF;       // shorts (= 84,934,656)

  float* wsF  = (float*)d_ws;
  long fBase  = wEnd / 2;                       // float index (wEnd even)
  float* h    = wsF + fBase;                    // HD f32 residual
  float* attn = h + HD;
  float* t1   = attn + HD;                      // split-K accumulator
  long sBase  = 2 * (fBase + 3 * HD);           // short index
  short* hb    = wsS + sBase;                   // HD bf16
  short* attnb = hb + HD;
  short* qkvb  = attnb + HD;                    // [3][B,H,S,DH]
  short* ctxb  = qkvb + 3 * HD;
  short* inter = ctxb + HD;                     // [B,S,FF]

  // --- once per call: zero the atomic accumulator, transpose weights ---
  hipMemsetAsync(t1, 0, HD * sizeof(float), stream);
  wtr_k<<<dim3(Dc / 64, Dc / 64, Lc), 256, 0, stream>>>(Wq, WqT, Dc, Dc);
  wtr_k<<<dim3(Dc / 64, Dc / 64, Lc), 256, 0, stream>>>(Wk, WkT, Dc, Dc);
  wtr_k<<<dim3(Dc / 64, Dc / 64, Lc), 256, 0, stream>>>(Wv, WvT, Dc, Dc);
  wtr_k<<<dim3(Dc / 64, Dc / 64, Lc), 256, 0, stream>>>(Wo, WoT, Dc, Dc);
  wtr_k<<<dim3(Dc / 64, FFc / 64, Lc), 256, 0, stream>>>(Wi, WiT, Dc, FFc);
  wtr_k<<<dim3(FFc / 64, Dc / 64, Lc), 256, 0, stream>>>(Wf, WfT, FFc, Dc);

  embed_k<<<Bc * Sc, 256, 0, stream>>>(ids, we, pe, te, elg, elb, h, hb);

  for (int l = 0; l < Lc; ++l) {
    // QKV: z selects W/bias; out bf16 [3][B,H,S,DH]
    gemm_k<EP_QKV><<<dim3(6, 32, 3), 256, 0, stream>>>(
        hb, Dc, WqT + l * DD, WkT + l * DD, WvT + l * DD, qkvb,
        bq + l * Dc, bk + l * Dc, bv + l * Dc, Dc, Dc);

    // fused flash attention -> ctx bf16 [B,S,D]
    attn_k<<<dim3(4, 96), 256, 0, stream>>>(qkvb, amask, ctxb);

    // ctx @ Wo, split-K=2, atomic accumulate into t1
    gemm_k<EP_ATOM><<<dim3(6, 32, 2), 256, 0, stream>>>(
        ctxb, Dc, WoT + l * DD, nullptr, nullptr, t1,
        nullptr, nullptr, nullptr, Dc, Dc / 2);

    // attn = LN(t1 + bo + h)  (re-zeros t1)
    red_ln_k<<<Bc * Sc, 256, 0, stream>>>(t1, h, bo + l * Dc,
                                          l1g + l * Dc, l1b + l * Dc, attn, attnb);

    // inter = gelu(attn @ Wi + bi) -> bf16
    gemm_k<EP_GELU><<<dim3(24, 32, 1), 256, 0, stream>>>(
        attnb, Dc, WiT + l * DF, nullptr, nullptr, inter,
        bi + l * FFc, nullptr, nullptr, FFc, Dc);

    // inter @ Wf, split-K=4, atomic accumulate into t1
    gemm_k<EP_ATOM><<<dim3(6, 32, 4), 256, 0, stream>>>(
        inter, FFc, WfT + l * DF, nullptr, nullptr, t1,
        nullptr, nullptr, nullptr, Dc, FFc / 4);

    // h = LN(t1 + bf + attn)  (re-zeros t1)
    red_ln_k<<<Bc * Sc, 256, 0, stream>>>(t1, attn, bfp + l * Dc,
                                          l2g + l * Dc, l2b + l * Dc, h, hb);
  }

  // mean-pool (two-phase, 128+8 blocks) + L2 normalize.
  pool1_k<<<dim3(16, Bc), 256, 0, stream>>>(h, amask, attn);
  pool2_k<<<Bc, 256, 0, stream>>>(attn, amask, out);
}

// Round 4
// 2686.508 us; speedup vs baseline: 1.4698x; 1.0287x over previous
//
#include <hip/hip_runtime.h>
#include <math.h>

// ---- model constants (fixed problem size) ----
#define Bc   8
#define Sc   512
#define Dc   768
#define Hc   12
#define DHc  64
#define FFc  3072
#define Lc   12

typedef float  floatx4 __attribute__((ext_vector_type(4)));
typedef short  shortx8 __attribute__((ext_vector_type(8)));
typedef short  shortx4 __attribute__((ext_vector_type(4)));
typedef __bf16 bf16x8  __attribute__((ext_vector_type(8)));

__device__ __forceinline__ short f2bf(float f) {
  union { float f; unsigned u; } x; x.f = f;
  unsigned r = x.u + 0x7fffu + ((x.u >> 16) & 1u);   // RNE
  return (short)(r >> 16);
}

// fast exact-GELU: erf via Abramowitz-Stegun 7.1.26 (|eps| <= 1.5e-7).
// gelu abs error <= |v|*7.5e-8 -- invisible under bf16 output rounding.
__device__ __forceinline__ float gelu_f(float v) {
  float x  = v * 0.70710678118654752f;
  float ax = fabsf(x);
  float t  = 1.0f / (1.0f + 0.3275911f * ax);
  float p  = t * (0.254829592f + t * (-0.284496736f + t * (1.421413741f +
             t * (-1.453152027f + t * 1.061405429f))));
  float er = 1.0f - p * __expf(-ax * ax);
  er = (x < 0.f) ? -er : er;
  return 0.5f * v * (1.0f + er);
}

// async global->LDS, 16B per lane. LDS dest must be wave-uniform base;
// HW writes base + lane*16. Global src is per-lane.
__device__ __forceinline__ void gl16(const void* g, void* l) {
  __builtin_amdgcn_global_load_lds(
      (const __attribute__((address_space(1))) void*)g,
      (__attribute__((address_space(3))) void*)l, 16, 0, 0);
}

// ---------------- weight transpose+convert: W f32 [K,N] -> Wt bf16 [N,K] ----
__global__ __launch_bounds__(256)
void wtr_k(const float* __restrict__ W, short* __restrict__ Wt, int K, int N) {
  __shared__ short sT[64 * 72];
  const int k0 = blockIdx.x * 64, n0 = blockIdx.y * 64;
  const long base = (long)blockIdx.z * K * N;
  W  += base;
  Wt += base;
  const int t = threadIdx.x;
  {
    int kr = t >> 4, nc = (t & 15) * 4;
    #pragma unroll
    for (int i = 0; i < 4; ++i) {
      int k = kr + i * 16;
      float4 v = *(const float4*)(W + (long)(k0 + k) * N + n0 + nc);
      shortx4 p; p.x = f2bf(v.x); p.y = f2bf(v.y); p.z = f2bf(v.z); p.w = f2bf(v.w);
      *(shortx4*)(sT + k * 72 + nc) = p;
    }
  }
  __syncthreads();
  {
    int nr = t >> 3, kc = (t & 7) * 8;
    #pragma unroll
    for (int i = 0; i < 2; ++i) {
      int n = nr + i * 32;
      shortx8 p;
      #pragma unroll
      for (int j = 0; j < 8; ++j) p[j] = sT[(kc + j) * 72 + n];
      *(shortx8*)(Wt + (long)(n0 + n) * K + k0 + kc) = p;
    }
  }
}

// ---------------- dense GEMM ----------------
// C[M,N] = A[M,K] @ B^T  (A bf16 [M][lda], B bf16 pre-transposed [N][lda]),
// tile 128x128x64, 256 threads = 4 waves 2x2, wave 64x64 via 4x4 MFMA 16x16x32.
// Staging via global_load_lds width=16 into LINEAR [128][64] LDS with an
// XOR-16B swizzle applied BOTH sides (rule #21). XCD-aware bijective block
// swizzle (T1): each XCD walks bx fastest over a fixed A-panel.

enum { EP_QKV, EP_ATOM, EP_GELU };

template<int EP>
__global__ __launch_bounds__(256, 3)
void gemm_k(const short* __restrict__ A, int lda,
            const short* __restrict__ B0, const short* __restrict__ B1,
            const short* __restrict__ B2,
            void* __restrict__ Cp,
            const float* __restrict__ bias0, const float* __restrict__ bias1,
            const float* __restrict__ bias2,
            int Nn, int Ksplit)
{
  __shared__ short sA[128 * 64];
  __shared__ short sB[128 * 64];

  const int tid = threadIdx.x;

  // ---- XCD swizzle: grids are (GX, 32, gz), all sizes divisible by 8 ----
  constexpr int GX = (EP == EP_GELU) ? 24 : 6;   // n-tiles (hardcoded grids)
  const int gz   = gridDim.z;
  const int nwg  = GX * 32 * gz;
  const int orig = blockIdx.x + GX * (blockIdx.y + 32 * blockIdx.z);
  const int wid  = (orig & 7) * (nwg >> 3) + (orig >> 3);
  const int bx   = wid % GX;
  const int rest = wid / GX;
  const int z    = rest >> 5;          // rest / 32
  const int m0   = (rest & 31) * 128;
  const int n0   = bx * 128;

  const short* Bw;
  const float* bias;
  int kbase;
  if (EP == EP_QKV) {
    Bw   = (z == 0) ? B0 : (z == 1 ? B1 : B2);
    bias = (z == 0) ? bias0 : (z == 1 ? bias1 : bias2);
    kbase = 0;
  } else {
    Bw = B0; bias = bias0; kbase = z * Ksplit;
  }

  const short* Ag = A  + (long)m0 * lda + kbase;
  const short* Bg = Bw + (long)n0 * lda + kbase;

  floatx4 acc[4][4];
  #pragma unroll
  for (int i = 0; i < 4; ++i)
    #pragma unroll
    for (int j = 0; j < 4; ++j) acc[i][j] = (floatx4)0.f;

  const int wave = tid >> 6, lane = tid & 63;
  const int wm = (wave >> 1) * 64, wn = (wave & 1) * 64;
  const int quad = lane >> 4, r16 = lane & 15;

  // staging geometry: wave w, iter i covers rows (w*4+i)*8 .. +8 of the tile.
  // lane l -> row offset l>>3, swizzled col (shorts) 8*((l&7)^(l>>3)).
  const int srow = lane >> 3;                    // 0..7
  const int scol = 8 * ((lane & 7) ^ srow);      // pre-swizzled source col

  const int nkt = Ksplit / 64;
  for (int kt = 0; kt < nkt; ++kt) {
    const long ko_g = (long)kt * 64;
    #pragma unroll
    for (int i = 0; i < 4; ++i) {
      int rb = (wave * 4 + i) * 8;               // tile row base of this 1KB chunk
      gl16(Ag + (long)(rb + srow) * lda + ko_g + scol, sA + (wave * 4 + i) * 512);
    }
    #pragma unroll
    for (int i = 0; i < 4; ++i) {
      int rb = (wave * 4 + i) * 8;
      gl16(Bg + (long)(rb + srow) * lda + ko_g + scol, sB + (wave * 4 + i) * 512);
    }
    __syncthreads();

    #pragma unroll
    for (int kc = 0; kc < 2; ++kc) {
      const int ko = kc * 32 + quad * 8;
      bf16x8 af[4], bv[4];
      #pragma unroll
      for (int mi = 0; mi < 4; ++mi) {
        int row = wm + mi * 16 + r16;
        af[mi] = __builtin_bit_cast(bf16x8,
            *(const shortx8*)(sA + row * 64 + (ko ^ (8 * (row & 7)))));
      }
      #pragma unroll
      for (int ni = 0; ni < 4; ++ni) {
        int row = wn + ni * 16 + r16;
        bv[ni] = __builtin_bit_cast(bf16x8,
            *(const shortx8*)(sB + row * 64 + (ko ^ (8 * (row & 7)))));
      }
      #pragma unroll
      for (int mi = 0; mi < 4; ++mi)
        #pragma unroll
        for (int ni = 0; ni < 4; ++ni)
          acc[mi][ni] = __builtin_amdgcn_mfma_f32_16x16x32_bf16(af[mi], bv[ni], acc[mi][ni], 0, 0, 0);
    }
    __syncthreads();
  }

  // ---- epilogue: C/D layout col=lane&15, row=quad*4+reg ----
  #pragma unroll
  for (int mi = 0; mi < 4; ++mi) {
    #pragma unroll
    for (int ni = 0; ni < 4; ++ni) {
      #pragma unroll
      for (int r = 0; r < 4; ++r) {
        int mm = m0 + wm + mi * 16 + quad * 4 + r;
        int nn = n0 + wn + ni * 16 + r16;
        float v = acc[mi][ni][r];
        if (EP == EP_QKV) {
          v += bias[nn];
          int b = mm >> 9, s = mm & 511;
          int hh = nn >> 6, dd = nn & 63;
          ((short*)Cp)[((((long)z * Bc + b) * Hc + hh) * Sc + s) * DHc + dd] = f2bf(v);
        } else if (EP == EP_ATOM) {
          atomicAdd(&((float*)Cp)[(long)mm * Nn + nn], v);
        } else if (EP == EP_GELU) {
          v += bias[nn];
          ((short*)Cp)[(long)mm * Nn + nn] = f2bf(gelu_f(v));
        }
      }
    }
  }
}

// ---------------- fused flash attention (unchanged) ----------------
#define HDL ((long)Bc * Hc * Sc * DHc)

__global__ __launch_bounds__(256, 2)
void attn_k(const short* __restrict__ qkv, const int* __restrict__ msk,
            short* __restrict__ ctx)
{
  __shared__ short sQ[128 * 72];
  __shared__ short sK[64 * 72];
  __shared__ short sV[64 * 72];   // transposed [dh][kn], rotated
  __shared__ short sP[128 * 72];

  const int tid = threadIdx.x;
  const int qt = blockIdx.x, bh = blockIdx.y;
  const int b = bh / Hc, hh = bh % Hc;
  const int wave = tid >> 6, lane = tid & 63;
  const int quad = lane >> 4, r16 = lane & 15;

  const short* Qg = qkv + ((long)bh * Sc + qt * 128) * DHc;
  const short* Kg = qkv + HDL + (long)bh * Sc * DHc;
  const short* Vg = qkv + 2 * HDL + (long)bh * Sc * DHc;

  #pragma unroll
  for (int i = 0; i < 4; ++i) {
    int id = tid + i * 256;
    int r = id >> 3, c = (id & 7) * 8;
    *(shortx8*)(sQ + r * 72 + c) = *(const shortx8*)(Qg + r * 64 + c);
  }

  floatx4 o[2][4];
  float m_old[2][4], l[2][4];
  #pragma unroll
  for (int mi = 0; mi < 2; ++mi) {
    #pragma unroll
    for (int nj = 0; nj < 4; ++nj) o[mi][nj] = (floatx4)0.f;
    #pragma unroll
    for (int r = 0; r < 4; ++r) { m_old[mi][r] = -3.0e38f; l[mi][r] = 0.f; }
  }

  for (int kt = 0; kt < 8; ++kt) {
    __syncthreads();
    #pragma unroll
    for (int i = 0; i < 2; ++i) {
      int id = tid + i * 256;
      int r = id >> 3, c = (id & 7) * 8;
      *(shortx8*)(sK + r * 72 + c) = *(const shortx8*)(Kg + (kt * 64 + r) * 64 + c);
    }
    #pragma unroll
    for (int i = 0; i < 2; ++i) {
      int id = tid + i * 256;
      int r = id >> 3, c8 = id & 7;
      shortx8 v = *(const shortx8*)(Vg + (kt * 64 + r) * 64 + c8 * 8);
      #pragma unroll
      for (int j = 0; j < 8; ++j) {
        int kn2 = (r + 8 * ((j + c8) & 7)) & 63;
        sV[(c8 * 8 + j) * 72 + kn2] = v[j];
      }
    }
    __syncthreads();

    floatx4 s[2][4];
    #pragma unroll
    for (int mi = 0; mi < 2; ++mi)
      #pragma unroll
      for (int ni = 0; ni < 4; ++ni) s[mi][ni] = (floatx4)0.f;
    #pragma unroll
    for (int kc = 0; kc < 2; ++kc) {
      const int ko = kc * 32 + quad * 8;
      bf16x8 aq[2], bk[4];
      #pragma unroll
      for (int mi = 0; mi < 2; ++mi)
        aq[mi] = __builtin_bit_cast(bf16x8, *(const shortx8*)(sQ + (wave * 32 + mi * 16 + r16) * 72 + ko));
      #pragma unroll
      for (int ni = 0; ni < 4; ++ni)
        bk[ni] = __builtin_bit_cast(bf16x8, *(const shortx8*)(sK + (ni * 16 + r16) * 72 + ko));
      #pragma unroll
      for (int mi = 0; mi < 2; ++mi)
        #pragma unroll
        for (int ni = 0; ni < 4; ++ni)
          s[mi][ni] = __builtin_amdgcn_mfma_f32_16x16x32_bf16(aq[mi], bk[ni], s[mi][ni], 0, 0, 0);
    }

    float mv[4];
    #pragma unroll
    for (int ni = 0; ni < 4; ++ni)
      mv[ni] = (float)msk[b * Sc + kt * 64 + ni * 16 + r16];

    #pragma unroll
    for (int mi = 0; mi < 2; ++mi) {
      #pragma unroll
      for (int r = 0; r < 4; ++r) {
        float mx = fmaxf(fmaxf(s[mi][0][r], s[mi][1][r]), fmaxf(s[mi][2][r], s[mi][3][r]));
        mx *= 0.125f;
        #pragma unroll
        for (int off = 1; off <= 8; off <<= 1) mx = fmaxf(mx, __shfl_xor(mx, off));
        float mn = fmaxf(m_old[mi][r], mx);
        float al = __expf(m_old[mi][r] - mn);
        m_old[mi][r] = mn;
        float rs = 0.f;
        #pragma unroll
        for (int ni = 0; ni < 4; ++ni) {
          float p = __expf(fmaf(s[mi][ni][r], 0.125f, -mn)) * mv[ni];
          s[mi][ni][r] = p;
          rs += p;
        }
        #pragma unroll
        for (int off = 1; off <= 8; off <<= 1) rs += __shfl_xor(rs, off);
        l[mi][r] = l[mi][r] * al + rs;
        #pragma unroll
        for (int nj = 0; nj < 4; ++nj) o[mi][nj][r] *= al;
        int row = wave * 32 + mi * 16 + quad * 4 + r;
        #pragma unroll
        for (int ni = 0; ni < 4; ++ni)
          sP[row * 72 + ni * 16 + r16] = f2bf(s[mi][ni][r]);
      }
    }
    __syncthreads();

    #pragma unroll
    for (int kc = 0; kc < 2; ++kc) {
      const int ko = kc * 32 + quad * 8;
      bf16x8 ap[2], bv[4];
      #pragma unroll
      for (int mi = 0; mi < 2; ++mi)
        ap[mi] = __builtin_bit_cast(bf16x8, *(const shortx8*)(sP + (wave * 32 + mi * 16 + r16) * 72 + ko));
      #pragma unroll
      for (int nj = 0; nj < 4; ++nj) {
        int dh = nj * 16 + r16;
        int f = (dh + (dh >> 3)) & 7;
        int base = (ko + 8 * f) & 63;
        bv[nj] = __builtin_bit_cast(bf16x8, *(const shortx8*)(sV + dh * 72 + base));
      }
      #pragma unroll
      for (int mi = 0; mi < 2; ++mi)
        #pragma unroll
        for (int nj = 0; nj < 4; ++nj)
          o[mi][nj] = __builtin_amdgcn_mfma_f32_16x16x32_bf16(ap[mi], bv[nj], o[mi][nj], 0, 0, 0);
    }
  }

  #pragma unroll
  for (int mi = 0; mi < 2; ++mi) {
    #pragma unroll
    for (int r = 0; r < 4; ++r) {
      float inv = 1.f / fmaxf(l[mi][r], 1e-20f);
      int row = qt * 128 + wave * 32 + mi * 16 + quad * 4 + r;
      #pragma unroll
      for (int nj = 0; nj < 4; ++nj) {
        int col = hh * 64 + nj * 16 + r16;
        ctx[((long)b * Sc + row) * Dc + col] = f2bf(o[mi][nj][r] * inv);
      }
    }
  }
}

// ---------------- reductions / LN ----------------
__device__ __forceinline__ void block_red2(float& s, float& ss) {
  #pragma unroll
  for (int off = 32; off; off >>= 1) {
    s  += __shfl_xor(s, off);
    ss += __shfl_xor(ss, off);
  }
  __shared__ float rs[4], rss[4];
  int wave = threadIdx.x >> 6, lane = threadIdx.x & 63;
  __syncthreads();
  if (lane == 0) { rs[wave] = s; rss[wave] = ss; }
  __syncthreads();
  s  = rs[0] + rs[1] + rs[2] + rs[3];
  ss = rss[0] + rss[1] + rss[2] + rss[3];
}

__device__ __forceinline__ void ln3_dual(float a0, float a1, float a2,
                                         const float* __restrict__ g,
                                         const float* __restrict__ bb,
                                         float* __restrict__ outf,
                                         short* __restrict__ outb, int tid) {
  float s = a0 + a1 + a2;
  float ss = a0 * a0 + a1 * a1 + a2 * a2;
  block_red2(s, ss);
  float mu  = s * (1.f / 768.f);
  float var = ss * (1.f / 768.f) - mu * mu;
  float rstd = rsqrtf(var + 1e-12f);
  float y0 = (a0 - mu) * rstd * g[tid]       + bb[tid];
  float y1 = (a1 - mu) * rstd * g[tid + 256] + bb[tid + 256];
  float y2 = (a2 - mu) * rstd * g[tid + 512] + bb[tid + 512];
  outf[tid] = y0; outf[tid + 256] = y1; outf[tid + 512] = y2;
  outb[tid] = f2bf(y0); outb[tid + 256] = f2bf(y1); outb[tid + 512] = f2bf(y2);
}

// reduce (from atomically-accumulated t1) + bias + residual + LN; re-zeros t1
__global__ __launch_bounds__(256)
void red_ln_k(float* __restrict__ t1, const float* __restrict__ res,
              const float* __restrict__ bias,
              const float* __restrict__ g, const float* __restrict__ bb,
              float* __restrict__ outf, short* __restrict__ outb) {
  long base = (long)blockIdx.x * Dc;
  int tid = threadIdx.x;
  float a0 = t1[base + tid]       + bias[tid]       + res[base + tid];
  float a1 = t1[base + tid + 256] + bias[tid + 256] + res[base + tid + 256];
  float a2 = t1[base + tid + 512] + bias[tid + 512] + res[base + tid + 512];
  t1[base + tid] = 0.f; t1[base + tid + 256] = 0.f; t1[base + tid + 512] = 0.f;
  ln3_dual(a0, a1, a2, g, bb, outf + base, outb + base, tid);
}

__global__ __launch_bounds__(256)
void embed_k(const int* __restrict__ ids, const float* __restrict__ we,
             const float* __restrict__ pe, const float* __restrict__ te,
             const float* __restrict__ g, const float* __restrict__ bb,
             float* __restrict__ y, short* __restrict__ yb) {
  int row = blockIdx.x, tid = threadIdx.x;
  int s = row & 511;
  long wo = (long)ids[row] * Dc;
  long po = (long)s * Dc;
  float a0 = we[wo + tid]       + pe[po + tid]       + te[tid];
  float a1 = we[wo + tid + 256] + pe[po + tid + 256] + te[tid + 256];
  float a2 = we[wo + tid + 512] + pe[po + tid + 512] + te[tid + 512];
  ln3_dual(a0, a1, a2, g, bb, y + (long)row * Dc, yb + (long)row * Dc, tid);
}

// ---------------- mean pooling, two-phase (parallelized) ----------------
__global__ __launch_bounds__(256)
void pool1_k(const float* __restrict__ h, const int* __restrict__ msk,
             float* __restrict__ part) {
  const int chunk = blockIdx.x, b = blockIdx.y, tid = threadIdx.x;
  const float* hb = h + ((long)b * Sc + chunk * 32) * Dc;
  const int*   mb = msk + b * Sc + chunk * 32;
  float a0 = 0.f, a1 = 0.f, a2 = 0.f;
  for (int s = 0; s < 32; ++s) {
    float mk = (float)mb[s];
    if (mk != 0.f) {
      const float* hr = hb + (long)s * Dc;
      a0 += hr[tid] * mk; a1 += hr[tid + 256] * mk; a2 += hr[tid + 512] * mk;
    }
  }
  float* pr = part + (long)(b * 16 + chunk) * Dc;
  pr[tid] = a0; pr[tid + 256] = a1; pr[tid + 512] = a2;
}

__global__ __launch_bounds__(256)
void pool2_k(const float* __restrict__ part, const int* __restrict__ msk,
             float* __restrict__ out) {
  const int b = blockIdx.x, tid = threadIdx.x;
  float cnt = 0.f, d0 = 0.f;
  for (int s = tid; s < Sc; s += 256) cnt += (float)msk[b * Sc + s];
  block_red2(cnt, d0);
  float a0 = 0.f, a1 = 0.f, a2 = 0.f;
  const float* pb = part + (long)b * 16 * Dc;
  #pragma unroll
  for (int c = 0; c < 16; ++c) {
    a0 += pb[c * Dc + tid];
    a1 += pb[c * Dc + tid + 256];
    a2 += pb[c * Dc + tid + 512];
  }
  float dn = 1.f / fmaxf(cnt, 1e-6f);
  a0 *= dn; a1 *= dn; a2 *= dn;
  float ssq = a0 * a0 + a1 * a1 + a2 * a2, d1 = 0.f;
  block_red2(ssq, d1);
  float rn = 1.f / fmaxf(sqrtf(ssq), 1e-12f);
  out[b * Dc + tid]       = a0 * rn;
  out[b * Dc + tid + 256] = a1 * rn;
  out[b * Dc + tid + 512] = a2 * rn;
}

// ---------------- launcher ----------------
extern "C" void kernel_launch(void* const* d_in, const int* in_sizes, int n_in,
                              void* d_out, int out_size, void* d_ws, size_t ws_size,
                              hipStream_t stream)
{
  const int*   ids   = (const int*)d_in[0];
  const int*   amask = (const int*)d_in[1];
  const float* we    = (const float*)d_in[2];
  const float* pe    = (const float*)d_in[3];
  const float* te    = (const float*)d_in[4];
  const float* elg   = (const float*)d_in[5];
  const float* elb   = (const float*)d_in[6];
  const float* Wq    = (const float*)d_in[7];
  const float* bq    = (const float*)d_in[8];
  const float* Wk    = (const float*)d_in[9];
  const float* bk    = (const float*)d_in[10];
  const float* Wv    = (const float*)d_in[11];
  const float* bv    = (const float*)d_in[12];
  const float* Wo    = (const float*)d_in[13];
  const float* bo    = (const float*)d_in[14];
  const float* l1g   = (const float*)d_in[15];
  const float* l1b   = (const float*)d_in[16];
  const float* Wi    = (const float*)d_in[17];
  const float* bi    = (const float*)d_in[18];
  const float* Wf    = (const float*)d_in[19];
  const float* bfp   = (const float*)d_in[20];
  const float* l2g   = (const float*)d_in[21];
  const float* l2b   = (const float*)d_in[22];
  float* out = (float*)d_out;

  const long HD = (long)Bc * Sc * Dc;        // 3,145,728
  const long DD = (long)Dc * Dc;             // 589,824
  const long DF = (long)Dc * FFc;            // 2,359,296

  // --- workspace layout ---
  short* wsS = (short*)d_ws;
  short* WqT = wsS;                 // [L][768][768]
  short* WkT = WqT + Lc * DD;
  short* WvT = WkT + Lc * DD;
  short* WoT = WvT + Lc * DD;
  short* WiT = WoT + Lc * DD;       // [L][3072][768]
  short* WfT = WiT + Lc * DF;       // [L][768][3072]
  long wEnd = 4 * Lc * DD + 2 * Lc * DF;       // shorts (= 84,934,656)

  float* wsF  = (float*)d_ws;
  long fBase  = wEnd / 2;                       // float index (wEnd even)
  float* h    = wsF + fBase;                    // HD f32 residual
  float* attn = h + HD;
  float* t1   = attn + HD;                      // split-K accumulator
  long sBase  = 2 * (fBase + 3 * HD);           // short index
  short* hb    = wsS + sBase;                   // HD bf16
  short* attnb = hb + HD;
  short* qkvb  = attnb + HD;                    // [3][B,H,S,DH]
  short* ctxb  = qkvb + 3 * HD;
  short* inter = ctxb + HD;                     // [B,S,FF]

  // --- once per call: zero the atomic accumulator, transpose weights ---
  hipMemsetAsync(t1, 0, HD * sizeof(float), stream);
  wtr_k<<<dim3(Dc / 64, Dc / 64, Lc), 256, 0, stream>>>(Wq, WqT, Dc, Dc);
  wtr_k<<<dim3(Dc / 64, Dc / 64, Lc), 256, 0, stream>>>(Wk, WkT, Dc, Dc);
  wtr_k<<<dim3(Dc / 64, Dc / 64, Lc), 256, 0, stream>>>(Wv, WvT, Dc, Dc);
  wtr_k<<<dim3(Dc / 64, Dc / 64, Lc), 256, 0, stream>>>(Wo, WoT, Dc, Dc);
  wtr_k<<<dim3(Dc / 64, FFc / 64, Lc), 256, 0, stream>>>(Wi, WiT, Dc, FFc);
  wtr_k<<<dim3(FFc / 64, Dc / 64, Lc), 256, 0, stream>>>(Wf, WfT, FFc, Dc);

  embed_k<<<Bc * Sc, 256, 0, stream>>>(ids, we, pe, te, elg, elb, h, hb);

  for (int l = 0; l < Lc; ++l) {
    // QKV: z selects W/bias; out bf16 [3][B,H,S,DH]
    gemm_k<EP_QKV><<<dim3(6, 32, 3), 256, 0, stream>>>(
        hb, Dc, WqT + l * DD, WkT + l * DD, WvT + l * DD, qkvb,
        bq + l * Dc, bk + l * Dc, bv + l * Dc, Dc, Dc);

    // fused flash attention -> ctx bf16 [B,S,D]
    attn_k<<<dim3(4, 96), 256, 0, stream>>>(qkvb, amask, ctxb);

    // ctx @ Wo, split-K=2, atomic accumulate into t1
    gemm_k<EP_ATOM><<<dim3(6, 32, 2), 256, 0, stream>>>(
        ctxb, Dc, WoT + l * DD, nullptr, nullptr, t1,
        nullptr, nullptr, nullptr, Dc, Dc / 2);

    // attn = LN(t1 + bo + h)  (re-zeros t1)
    red_ln_k<<<Bc * Sc, 256, 0, stream>>>(t1, h, bo + l * Dc,
                                          l1g + l * Dc, l1b + l * Dc, attn, attnb);

    // inter = gelu(attn @ Wi + bi) -> bf16
    gemm_k<EP_GELU><<<dim3(24, 32, 1), 256, 0, stream>>>(
        attnb, Dc, WiT + l * DF, nullptr, nullptr, inter,
        bi + l * FFc, nullptr, nullptr, FFc, Dc);

    // inter @ Wf, split-K=4, atomic accumulate into t1
    gemm_k<EP_ATOM><<<dim3(6, 32, 4), 256, 0, stream>>>(
        inter, FFc, WfT + l * DF, nullptr, nullptr, t1,
        nullptr, nullptr, nullptr, Dc, FFc / 4);

    // h = LN(t1 + bf + attn)  (re-zeros t1)
    red_ln_k<<<Bc * Sc, 256, 0, stream>>>(t1, attn, bfp + l * Dc,
                                          l2g + l * Dc, l2b + l * Dc, h, hb);
  }

  // mean-pool (two-phase, 128+8 blocks) + L2 normalize.
  pool1_k<<<dim3(16, Bc), 256, 0, stream>>>(h, amask, attn);
  pool2_k<<<Bc, 256, 0, stream>>>(attn, amask, out);
}

// Round 5
// 2226.295 us; speedup vs baseline: 1.7736x; 1.2067x over previous
//
#include <hip/hip_runtime.h>
#include <math.h>

// ---- model constants (fixed problem size) ----
#define Bc   8
#define Sc   512
#define Dc   768
#define Hc   12
#define DHc  64
#define FFc  3072
#define Lc   12

typedef float  floatx4 __attribute__((ext_vector_type(4)));
typedef short  shortx8 __attribute__((ext_vector_type(8)));
typedef short  shortx4 __attribute__((ext_vector_type(4)));
typedef __bf16 bf16x8  __attribute__((ext_vector_type(8)));

__device__ __forceinline__ short f2bf(float f) {
  union { float f; unsigned u; } x; x.f = f;
  unsigned r = x.u + 0x7fffu + ((x.u >> 16) & 1u);   // RNE
  return (short)(r >> 16);
}

// fast exact-GELU: erf via Abramowitz-Stegun 7.1.26 (|eps| <= 1.5e-7).
__device__ __forceinline__ float gelu_f(float v) {
  float x  = v * 0.70710678118654752f;
  float ax = fabsf(x);
  float t  = 1.0f / (1.0f + 0.3275911f * ax);
  float p  = t * (0.254829592f + t * (-0.284496736f + t * (1.421413741f +
             t * (-1.453152027f + t * 1.061405429f))));
  float er = 1.0f - p * __expf(-ax * ax);
  er = (x < 0.f) ? -er : er;
  return 0.5f * v * (1.0f + er);
}

// async global->LDS, 16B per lane. LDS dest must be wave-uniform base;
// HW writes base + lane*16. Global src is per-lane.
__device__ __forceinline__ void gl16(const void* g, void* l) {
  __builtin_amdgcn_global_load_lds(
      (const __attribute__((address_space(1))) void*)g,
      (__attribute__((address_space(3))) void*)l, 16, 0, 0);
}

// ---------------- weight transpose+convert: W f32 [K,N] -> Wt bf16 [N,K] ----
__global__ __launch_bounds__(256)
void wtr_k(const float* __restrict__ W, short* __restrict__ Wt, int K, int N) {
  __shared__ short sT[64 * 72];
  const int k0 = blockIdx.x * 64, n0 = blockIdx.y * 64;
  const long base = (long)blockIdx.z * K * N;
  W  += base;
  Wt += base;
  const int t = threadIdx.x;
  {
    int kr = t >> 4, nc = (t & 15) * 4;
    #pragma unroll
    for (int i = 0; i < 4; ++i) {
      int k = kr + i * 16;
      float4 v = *(const float4*)(W + (long)(k0 + k) * N + n0 + nc);
      shortx4 p; p.x = f2bf(v.x); p.y = f2bf(v.y); p.z = f2bf(v.z); p.w = f2bf(v.w);
      *(shortx4*)(sT + k * 72 + nc) = p;
    }
  }
  __syncthreads();
  {
    int nr = t >> 3, kc = (t & 7) * 8;
    #pragma unroll
    for (int i = 0; i < 2; ++i) {
      int n = nr + i * 32;
      shortx8 p;
      #pragma unroll
      for (int j = 0; j < 8; ++j) p[j] = sT[(kc + j) * 72 + n];
      *(shortx8*)(Wt + (long)(n0 + n) * K + k0 + kc) = p;
    }
  }
}

// ---------------- dense GEMM ----------------
// C[M,N] = A[M,K] @ B^T  (A bf16 [M][lda], B bf16 pre-transposed [N][lda]),
// tile 128x128x64, 256 threads = 4 waves 2x2, wave 64x64 via 4x4 MFMA 16x16x32.
// Staging via global_load_lds width=16, XOR-16B swizzle both sides (rule #21).
// XCD-aware bijective block swizzle. Split-K writes per-z f32 SLABS (plain
// stores, no atomics); red_ln sums the slabs.

enum { EP_QKV, EP_STORE, EP_GELU };

template<int EP>
__global__ __launch_bounds__(256, 3)
void gemm_k(const short* __restrict__ A, int lda,
            const short* __restrict__ B0, const short* __restrict__ B1,
            const short* __restrict__ B2,
            void* __restrict__ Cp,
            const float* __restrict__ bias0, const float* __restrict__ bias1,
            const float* __restrict__ bias2,
            float* __restrict__ s1, float* __restrict__ s2,
            float* __restrict__ s3,
            int Nn, int Ksplit)
{
  __shared__ short sA[128 * 64];
  __shared__ short sB[128 * 64];

  const int tid = threadIdx.x;

  // ---- XCD swizzle: grids are (GX, 32, gz), all nwg divisible by 8 ----
  constexpr int GX = (EP == EP_GELU) ? 24 : 6;
  const int gz   = gridDim.z;
  const int nwg  = GX * 32 * gz;
  const int orig = blockIdx.x + GX * (blockIdx.y + 32 * blockIdx.z);
  const int wid  = (orig & 7) * (nwg >> 3) + (orig >> 3);
  const int bx   = wid % GX;
  const int rest = wid / GX;
  const int z    = rest >> 5;          // rest / 32
  const int m0   = (rest & 31) * 128;
  const int n0   = bx * 128;

  const short* Bw;
  const float* bias;
  int kbase;
  if (EP == EP_QKV) {
    Bw   = (z == 0) ? B0 : (z == 1 ? B1 : B2);
    bias = (z == 0) ? bias0 : (z == 1 ? bias1 : bias2);
    kbase = 0;
  } else {
    Bw = B0; bias = bias0; kbase = z * Ksplit;
  }

  const short* Ag = A  + (long)m0 * lda + kbase;
  const short* Bg = Bw + (long)n0 * lda + kbase;

  floatx4 acc[4][4];
  #pragma unroll
  for (int i = 0; i < 4; ++i)
    #pragma unroll
    for (int j = 0; j < 4; ++j) acc[i][j] = (floatx4)0.f;

  const int wave = tid >> 6, lane = tid & 63;
  const int wm = (wave >> 1) * 64, wn = (wave & 1) * 64;
  const int quad = lane >> 4, r16 = lane & 15;

  const int srow = lane >> 3;                    // 0..7
  const int scol = 8 * ((lane & 7) ^ srow);      // pre-swizzled source col

  const int nkt = Ksplit / 64;
  for (int kt = 0; kt < nkt; ++kt) {
    const long ko_g = (long)kt * 64;
    #pragma unroll
    for (int i = 0; i < 4; ++i) {
      int rb = (wave * 4 + i) * 8;
      gl16(Ag + (long)(rb + srow) * lda + ko_g + scol, sA + (wave * 4 + i) * 512);
    }
    #pragma unroll
    for (int i = 0; i < 4; ++i) {
      int rb = (wave * 4 + i) * 8;
      gl16(Bg + (long)(rb + srow) * lda + ko_g + scol, sB + (wave * 4 + i) * 512);
    }
    __syncthreads();

    #pragma unroll
    for (int kc = 0; kc < 2; ++kc) {
      const int ko = kc * 32 + quad * 8;
      bf16x8 af[4], bv[4];
      #pragma unroll
      for (int mi = 0; mi < 4; ++mi) {
        int row = wm + mi * 16 + r16;
        af[mi] = __builtin_bit_cast(bf16x8,
            *(const shortx8*)(sA + row * 64 + (ko ^ (8 * (row & 7)))));
      }
      #pragma unroll
      for (int ni = 0; ni < 4; ++ni) {
        int row = wn + ni * 16 + r16;
        bv[ni] = __builtin_bit_cast(bf16x8,
            *(const shortx8*)(sB + row * 64 + (ko ^ (8 * (row & 7)))));
      }
      #pragma unroll
      for (int mi = 0; mi < 4; ++mi)
        #pragma unroll
        for (int ni = 0; ni < 4; ++ni)
          acc[mi][ni] = __builtin_amdgcn_mfma_f32_16x16x32_bf16(af[mi], bv[ni], acc[mi][ni], 0, 0, 0);
    }
    __syncthreads();
  }

  // ---- epilogue: C/D layout col=lane&15, row=quad*4+reg ----
  float* slab = nullptr;
  if (EP == EP_STORE)
    slab = (z == 0) ? (float*)Cp : (z == 1) ? s1 : (z == 2) ? s2 : s3;

  #pragma unroll
  for (int mi = 0; mi < 4; ++mi) {
    #pragma unroll
    for (int ni = 0; ni < 4; ++ni) {
      #pragma unroll
      for (int r = 0; r < 4; ++r) {
        int mm = m0 + wm + mi * 16 + quad * 4 + r;
        int nn = n0 + wn + ni * 16 + r16;
        float v = acc[mi][ni][r];
        if (EP == EP_QKV) {
          v += bias[nn];
          int b = mm >> 9, s = mm & 511;
          int hh = nn >> 6, dd = nn & 63;
          ((short*)Cp)[((((long)z * Bc + b) * Hc + hh) * Sc + s) * DHc + dd] = f2bf(v);
        } else if (EP == EP_STORE) {
          slab[(long)mm * Nn + nn] = v;
        } else if (EP == EP_GELU) {
          v += bias[nn];
          ((short*)Cp)[(long)mm * Nn + nn] = f2bf(gelu_f(v));
        }
      }
    }
  }
}

// ---------------- fused flash attention (unchanged) ----------------
#define HDL ((long)Bc * Hc * Sc * DHc)

__global__ __launch_bounds__(256, 2)
void attn_k(const short* __restrict__ qkv, const int* __restrict__ msk,
            short* __restrict__ ctx)
{
  __shared__ short sQ[128 * 72];
  __shared__ short sK[64 * 72];
  __shared__ short sV[64 * 72];   // transposed [dh][kn], rotated
  __shared__ short sP[128 * 72];

  const int tid = threadIdx.x;
  const int qt = blockIdx.x, bh = blockIdx.y;
  const int b = bh / Hc, hh = bh % Hc;
  const int wave = tid >> 6, lane = tid & 63;
  const int quad = lane >> 4, r16 = lane & 15;

  const short* Qg = qkv + ((long)bh * Sc + qt * 128) * DHc;
  const short* Kg = qkv + HDL + (long)bh * Sc * DHc;
  const short* Vg = qkv + 2 * HDL + (long)bh * Sc * DHc;

  #pragma unroll
  for (int i = 0; i < 4; ++i) {
    int id = tid + i * 256;
    int r = id >> 3, c = (id & 7) * 8;
    *(shortx8*)(sQ + r * 72 + c) = *(const shortx8*)(Qg + r * 64 + c);
  }

  floatx4 o[2][4];
  float m_old[2][4], l[2][4];
  #pragma unroll
  for (int mi = 0; mi < 2; ++mi) {
    #pragma unroll
    for (int nj = 0; nj < 4; ++nj) o[mi][nj] = (floatx4)0.f;
    #pragma unroll
    for (int r = 0; r < 4; ++r) { m_old[mi][r] = -3.0e38f; l[mi][r] = 0.f; }
  }

  for (int kt = 0; kt < 8; ++kt) {
    __syncthreads();
    #pragma unroll
    for (int i = 0; i < 2; ++i) {
      int id = tid + i * 256;
      int r = id >> 3, c = (id & 7) * 8;
      *(shortx8*)(sK + r * 72 + c) = *(const shortx8*)(Kg + (kt * 64 + r) * 64 + c);
    }
    #pragma unroll
    for (int i = 0; i < 2; ++i) {
      int id = tid + i * 256;
      int r = id >> 3, c8 = id & 7;
      shortx8 v = *(const shortx8*)(Vg + (kt * 64 + r) * 64 + c8 * 8);
      #pragma unroll
      for (int j = 0; j < 8; ++j) {
        int kn2 = (r + 8 * ((j + c8) & 7)) & 63;
        sV[(c8 * 8 + j) * 72 + kn2] = v[j];
      }
    }
    __syncthreads();

    floatx4 s[2][4];
    #pragma unroll
    for (int mi = 0; mi < 2; ++mi)
      #pragma unroll
      for (int ni = 0; ni < 4; ++ni) s[mi][ni] = (floatx4)0.f;
    #pragma unroll
    for (int kc = 0; kc < 2; ++kc) {
      const int ko = kc * 32 + quad * 8;
      bf16x8 aq[2], bk[4];
      #pragma unroll
      for (int mi = 0; mi < 2; ++mi)
        aq[mi] = __builtin_bit_cast(bf16x8, *(const shortx8*)(sQ + (wave * 32 + mi * 16 + r16) * 72 + ko));
      #pragma unroll
      for (int ni = 0; ni < 4; ++ni)
        bk[ni] = __builtin_bit_cast(bf16x8, *(const shortx8*)(sK + (ni * 16 + r16) * 72 + ko));
      #pragma unroll
      for (int mi = 0; mi < 2; ++mi)
        #pragma unroll
        for (int ni = 0; ni < 4; ++ni)
          s[mi][ni] = __builtin_amdgcn_mfma_f32_16x16x32_bf16(aq[mi], bk[ni], s[mi][ni], 0, 0, 0);
    }

    float mv[4];
    #pragma unroll
    for (int ni = 0; ni < 4; ++ni)
      mv[ni] = (float)msk[b * Sc + kt * 64 + ni * 16 + r16];

    #pragma unroll
    for (int mi = 0; mi < 2; ++mi) {
      #pragma unroll
      for (int r = 0; r < 4; ++r) {
        float mx = fmaxf(fmaxf(s[mi][0][r], s[mi][1][r]), fmaxf(s[mi][2][r], s[mi][3][r]));
        mx *= 0.125f;
        #pragma unroll
        for (int off = 1; off <= 8; off <<= 1) mx = fmaxf(mx, __shfl_xor(mx, off));
        float mn = fmaxf(m_old[mi][r], mx);
        float al = __expf(m_old[mi][r] - mn);
        m_old[mi][r] = mn;
        float rs = 0.f;
        #pragma unroll
        for (int ni = 0; ni < 4; ++ni) {
          float p = __expf(fmaf(s[mi][ni][r], 0.125f, -mn)) * mv[ni];
          s[mi][ni][r] = p;
          rs += p;
        }
        #pragma unroll
        for (int off = 1; off <= 8; off <<= 1) rs += __shfl_xor(rs, off);
        l[mi][r] = l[mi][r] * al + rs;
        #pragma unroll
        for (int nj = 0; nj < 4; ++nj) o[mi][nj][r] *= al;
        int row = wave * 32 + mi * 16 + quad * 4 + r;
        #pragma unroll
        for (int ni = 0; ni < 4; ++ni)
          sP[row * 72 + ni * 16 + r16] = f2bf(s[mi][ni][r]);
      }
    }
    __syncthreads();

    #pragma unroll
    for (int kc = 0; kc < 2; ++kc) {
      const int ko = kc * 32 + quad * 8;
      bf16x8 ap[2], bv[4];
      #pragma unroll
      for (int mi = 0; mi < 2; ++mi)
        ap[mi] = __builtin_bit_cast(bf16x8, *(const shortx8*)(sP + (wave * 32 + mi * 16 + r16) * 72 + ko));
      #pragma unroll
      for (int nj = 0; nj < 4; ++nj) {
        int dh = nj * 16 + r16;
        int f = (dh + (dh >> 3)) & 7;
        int base = (ko + 8 * f) & 63;
        bv[nj] = __builtin_bit_cast(bf16x8, *(const shortx8*)(sV + dh * 72 + base));
      }
      #pragma unroll
      for (int mi = 0; mi < 2; ++mi)
        #pragma unroll
        for (int nj = 0; nj < 4; ++nj)
          o[mi][nj] = __builtin_amdgcn_mfma_f32_16x16x32_bf16(ap[mi], bv[nj], o[mi][nj], 0, 0, 0);
    }
  }

  #pragma unroll
  for (int mi = 0; mi < 2; ++mi) {
    #pragma unroll
    for (int r = 0; r < 4; ++r) {
      float inv = 1.f / fmaxf(l[mi][r], 1e-20f);
      int row = qt * 128 + wave * 32 + mi * 16 + quad * 4 + r;
      #pragma unroll
      for (int nj = 0; nj < 4; ++nj) {
        int col = hh * 64 + nj * 16 + r16;
        ctx[((long)b * Sc + row) * Dc + col] = f2bf(o[mi][nj][r] * inv);
      }
    }
  }
}

// ---------------- reductions / LN ----------------
__device__ __forceinline__ void block_red2(float& s, float& ss) {
  #pragma unroll
  for (int off = 32; off; off >>= 1) {
    s  += __shfl_xor(s, off);
    ss += __shfl_xor(ss, off);
  }
  __shared__ float rs[4], rss[4];
  int wave = threadIdx.x >> 6, lane = threadIdx.x & 63;
  __syncthreads();
  if (lane == 0) { rs[wave] = s; rss[wave] = ss; }
  __syncthreads();
  s  = rs[0] + rs[1] + rs[2] + rs[3];
  ss = rss[0] + rss[1] + rss[2] + rss[3];
}

__device__ __forceinline__ void ln3_dual(float a0, float a1, float a2,
                                         const float* __restrict__ g,
                                         const float* __restrict__ bb,
                                         float* __restrict__ outf,
                                         short* __restrict__ outb, int tid) {
  float s = a0 + a1 + a2;
  float ss = a0 * a0 + a1 * a1 + a2 * a2;
  block_red2(s, ss);
  float mu  = s * (1.f / 768.f);
  float var = ss * (1.f / 768.f) - mu * mu;
  float rstd = rsqrtf(var + 1e-12f);
  float y0 = (a0 - mu) * rstd * g[tid]       + bb[tid];
  float y1 = (a1 - mu) * rstd * g[tid + 256] + bb[tid + 256];
  float y2 = (a2 - mu) * rstd * g[tid + 512] + bb[tid + 512];
  outf[tid] = y0; outf[tid + 256] = y1; outf[tid + 512] = y2;
  outb[tid] = f2bf(y0); outb[tid + 256] = f2bf(y1); outb[tid + 512] = f2bf(y2);
}

// sum NS split-K slabs + bias + residual + LN (no atomics, no re-zero).
template<int NS>
__global__ __launch_bounds__(256)
void red_ln_k(const float* __restrict__ p0, const float* __restrict__ p1,
              const float* __restrict__ p2, const float* __restrict__ p3,
              const float* __restrict__ res, const float* __restrict__ bias,
              const float* __restrict__ g, const float* __restrict__ bb,
              float* __restrict__ outf, short* __restrict__ outb) {
  long base = (long)blockIdx.x * Dc;
  int tid = threadIdx.x;
  float a0 = p0[base + tid], a1 = p0[base + tid + 256], a2 = p0[base + tid + 512];
  if (NS > 1) {
    a0 += p1[base + tid]; a1 += p1[base + tid + 256]; a2 += p1[base + tid + 512];
  }
  if (NS > 2) {
    a0 += p2[base + tid]; a1 += p2[base + tid + 256]; a2 += p2[base + tid + 512];
  }
  if (NS > 3) {
    a0 += p3[base + tid]; a1 += p3[base + tid + 256]; a2 += p3[base + tid + 512];
  }
  a0 += bias[tid]       + res[base + tid];
  a1 += bias[tid + 256] + res[base + tid + 256];
  a2 += bias[tid + 512] + res[base + tid + 512];
  ln3_dual(a0, a1, a2, g, bb, outf + base, outb + base, tid);
}

__global__ __launch_bounds__(256)
void embed_k(const int* __restrict__ ids, const float* __restrict__ we,
             const float* __restrict__ pe, const float* __restrict__ te,
             const float* __restrict__ g, const float* __restrict__ bb,
             float* __restrict__ y, short* __restrict__ yb) {
  int row = blockIdx.x, tid = threadIdx.x;
  int s = row & 511;
  long wo = (long)ids[row] * Dc;
  long po = (long)s * Dc;
  float a0 = we[wo + tid]       + pe[po + tid]       + te[tid];
  float a1 = we[wo + tid + 256] + pe[po + tid + 256] + te[tid + 256];
  float a2 = we[wo + tid + 512] + pe[po + tid + 512] + te[tid + 512];
  ln3_dual(a0, a1, a2, g, bb, y + (long)row * Dc, yb + (long)row * Dc, tid);
}

// ---------------- mean pooling, two-phase (parallelized) ----------------
__global__ __launch_bounds__(256)
void pool1_k(const float* __restrict__ h, const int* __restrict__ msk,
             float* __restrict__ part) {
  const int chunk = blockIdx.x, b = blockIdx.y, tid = threadIdx.x;
  const float* hb = h + ((long)b * Sc + chunk * 32) * Dc;
  const int*   mb = msk + b * Sc + chunk * 32;
  float a0 = 0.f, a1 = 0.f, a2 = 0.f;
  for (int s = 0; s < 32; ++s) {
    float mk = (float)mb[s];
    if (mk != 0.f) {
      const float* hr = hb + (long)s * Dc;
      a0 += hr[tid] * mk; a1 += hr[tid + 256] * mk; a2 += hr[tid + 512] * mk;
    }
  }
  float* pr = part + (long)(b * 16 + chunk) * Dc;
  pr[tid] = a0; pr[tid + 256] = a1; pr[tid + 512] = a2;
}

__global__ __launch_bounds__(256)
void pool2_k(const float* __restrict__ part, const int* __restrict__ msk,
             float* __restrict__ out) {
  const int b = blockIdx.x, tid = threadIdx.x;
  float cnt = 0.f, d0 = 0.f;
  for (int s = tid; s < Sc; s += 256) cnt += (float)msk[b * Sc + s];
  block_red2(cnt, d0);
  float a0 = 0.f, a1 = 0.f, a2 = 0.f;
  const float* pb = part + (long)b * 16 * Dc;
  #pragma unroll
  for (int c = 0; c < 16; ++c) {
    a0 += pb[c * Dc + tid];
    a1 += pb[c * Dc + tid + 256];
    a2 += pb[c * Dc + tid + 512];
  }
  float dn = 1.f / fmaxf(cnt, 1e-6f);
  a0 *= dn; a1 *= dn; a2 *= dn;
  float ssq = a0 * a0 + a1 * a1 + a2 * a2, d1 = 0.f;
  block_red2(ssq, d1);
  float rn = 1.f / fmaxf(sqrtf(ssq), 1e-12f);
  out[b * Dc + tid]       = a0 * rn;
  out[b * Dc + tid + 256] = a1 * rn;
  out[b * Dc + tid + 512] = a2 * rn;
}

// ---------------- launcher ----------------
extern "C" void kernel_launch(void* const* d_in, const int* in_sizes, int n_in,
                              void* d_out, int out_size, void* d_ws, size_t ws_size,
                              hipStream_t stream)
{
  const int*   ids   = (const int*)d_in[0];
  const int*   amask = (const int*)d_in[1];
  const float* we    = (const float*)d_in[2];
  const float* pe    = (const float*)d_in[3];
  const float* te    = (const float*)d_in[4];
  const float* elg   = (const float*)d_in[5];
  const float* elb   = (const float*)d_in[6];
  const float* Wq    = (const float*)d_in[7];
  const float* bq    = (const float*)d_in[8];
  const float* Wk    = (const float*)d_in[9];
  const float* bk    = (const float*)d_in[10];
  const float* Wv    = (const float*)d_in[11];
  const float* bv    = (const float*)d_in[12];
  const float* Wo    = (const float*)d_in[13];
  const float* bo    = (const float*)d_in[14];
  const float* l1g   = (const float*)d_in[15];
  const float* l1b   = (const float*)d_in[16];
  const float* Wi    = (const float*)d_in[17];
  const float* bi    = (const float*)d_in[18];
  const float* Wf    = (const float*)d_in[19];
  const float* bfp   = (const float*)d_in[20];
  const float* l2g   = (const float*)d_in[21];
  const float* l2b   = (const float*)d_in[22];
  float* out = (float*)d_out;

  const long HD = (long)Bc * Sc * Dc;        // 3,145,728
  const long DD = (long)Dc * Dc;             // 589,824
  const long DF = (long)Dc * FFc;            // 2,359,296

  // --- workspace layout (same footprint as before) ---
  short* wsS = (short*)d_ws;
  short* WqT = wsS;                 // [L][768][768]
  short* WkT = WqT + Lc * DD;
  short* WvT = WkT + Lc * DD;
  short* WoT = WvT + Lc * DD;
  short* WiT = WoT + Lc * DD;       // [L][3072][768]
  short* WfT = WiT + Lc * DF;       // [L][768][3072]
  long wEnd = 4 * Lc * DD + 2 * Lc * DF;       // shorts (= 84,934,656)

  float* wsF  = (float*)d_ws;
  long fBase  = wEnd / 2;                       // float index (wEnd even)
  float* h    = wsF + fBase;                    // HD f32 residual
  float* attn = h + HD;
  float* t1   = attn + HD;                      // split-K slab 0
  long sBase  = 2 * (fBase + 3 * HD);           // short index
  short* hb    = wsS + sBase;                   // HD bf16
  short* attnb = hb + HD;
  short* qkvb  = attnb + HD;                    // [3][B,H,S,DH]
  short* ctxb  = qkvb + 3 * HD;
  short* inter = ctxb + HD;                     // [B,S,FF]

  // Split-K slab aliases (all regions dead at time of use; see dataflow):
  //   t2 = qkvb[0 : 2*HD shorts)          (qkvb dead after attn_k)
  //   t3 = qkvb[2*HD : 3*HD) + ctxb       (contiguous; dead after Wo-gemm)
  //   t4 = h                              (old h dead after red_ln1;
  //                                        red_ln2 reads t4[i] before writing h[i])
  float* t2 = (float*)qkvb;
  float* t3 = t2 + HD;
  float* t4 = h;

  // --- once per call: transpose weights (no memset needed any more) ---
  wtr_k<<<dim3(Dc / 64, Dc / 64, Lc), 256, 0, stream>>>(Wq, WqT, Dc, Dc);
  wtr_k<<<dim3(Dc / 64, Dc / 64, Lc), 256, 0, stream>>>(Wk, WkT, Dc, Dc);
  wtr_k<<<dim3(Dc / 64, Dc / 64, Lc), 256, 0, stream>>>(Wv, WvT, Dc, Dc);
  wtr_k<<<dim3(Dc / 64, Dc / 64, Lc), 256, 0, stream>>>(Wo, WoT, Dc, Dc);
  wtr_k<<<dim3(Dc / 64, FFc / 64, Lc), 256, 0, stream>>>(Wi, WiT, Dc, FFc);
  wtr_k<<<dim3(FFc / 64, Dc / 64, Lc), 256, 0, stream>>>(Wf, WfT, FFc, Dc);

  embed_k<<<Bc * Sc, 256, 0, stream>>>(ids, we, pe, te, elg, elb, h, hb);

  for (int l = 0; l < Lc; ++l) {
    // QKV: z selects W/bias; out bf16 [3][B,H,S,DH]
    gemm_k<EP_QKV><<<dim3(6, 32, 3), 256, 0, stream>>>(
        hb, Dc, WqT + l * DD, WkT + l * DD, WvT + l * DD, qkvb,
        bq + l * Dc, bk + l * Dc, bv + l * Dc,
        nullptr, nullptr, nullptr, Dc, Dc);

    // fused flash attention -> ctx bf16 [B,S,D]
    attn_k<<<dim3(4, 96), 256, 0, stream>>>(qkvb, amask, ctxb);

    // ctx @ Wo, split-K=2 -> slabs {t1, t2} (plain stores)
    gemm_k<EP_STORE><<<dim3(6, 32, 2), 256, 0, stream>>>(
        ctxb, Dc, WoT + l * DD, nullptr, nullptr, t1,
        nullptr, nullptr, nullptr,
        t2, nullptr, nullptr, Dc, Dc / 2);

    // attn = LN(t1 + t2 + bo + h)
    red_ln_k<2><<<Bc * Sc, 256, 0, stream>>>(t1, t2, nullptr, nullptr,
                                             h, bo + l * Dc,
                                             l1g + l * Dc, l1b + l * Dc, attn, attnb);

    // inter = gelu(attn @ Wi + bi) -> bf16
    gemm_k<EP_GELU><<<dim3(24, 32, 1), 256, 0, stream>>>(
        attnb, Dc, WiT + l * DF, nullptr, nullptr, inter,
        bi + l * FFc, nullptr, nullptr,
        nullptr, nullptr, nullptr, FFc, Dc);

    // inter @ Wf, split-K=4 -> slabs {t1, t2, t3, t4=h} (plain stores)
    gemm_k<EP_STORE><<<dim3(6, 32, 4), 256, 0, stream>>>(
        inter, FFc, WfT + l * DF, nullptr, nullptr, t1,
        nullptr, nullptr, nullptr,
        t2, t3, t4, Dc, FFc / 4);

    // h = LN(t1 + t2 + t3 + t4 + bf + attn)  (t4 aliases h; read-before-write per index)
    red_ln_k<4><<<Bc * Sc, 256, 0, stream>>>(t1, t2, t3, t4,
                                             attn, bfp + l * Dc,
                                             l2g + l * Dc, l2b + l * Dc, h, hb);
  }

  // mean-pool (two-phase, 128+8 blocks) + L2 normalize.
  pool1_k<<<dim3(16, Bc), 256, 0, stream>>>(h, amask, attn);
  pool2_k<<<Bc, 256, 0, stream>>>(attn, amask, out);
}